// Round 6
// baseline (199.316 us; speedup 1.0000x reference)
//
#include <hip/hip_runtime.h>

#define N_PIX 4096
#define CCH 256
#define DV 128

typedef __attribute__((ext_vector_type(8))) short bf16x8;
typedef __attribute__((ext_vector_type(4))) float f32x4;
typedef __attribute__((ext_vector_type(8))) short short8;

__device__ __forceinline__ short f2bf(float f) {
    unsigned u = __builtin_bit_cast(unsigned, f);
    u += 0x7fffu + ((u >> 16) & 1u);
    return (short)(u >> 16);
}

// ---------------------------------------------------------------------------
// K1: fused 1x1 convs (register-tiled fp32 GEMM, W staged in LDS) ->
//     qb[ib][n][16] bf16, kb[ib][n][16] bf16, vb[ib][c][N] bf16
// ---------------------------------------------------------------------------
__global__ __launch_bounds__(256) void qkv_kernel(
    const float* __restrict__ x1, const float* __restrict__ x2,
    const float* __restrict__ Wq, const float* __restrict__ bq,
    const float* __restrict__ Wk, const float* __restrict__ bk,
    const float* __restrict__ Wv, const float* __restrict__ bv,
    short* __restrict__ qb, short* __restrict__ kb, short* __restrict__ vb)
{
    __shared__ float xs[64][64];
    __shared__ float wsm[160][65];
    const int tid = threadIdx.x;
    const int n0 = blockIdx.x * 64;
    const int i = blockIdx.y >> 1, b = blockIdx.y & 1;
    const float* x = (i == 0 ? x1 : x2) + (size_t)b * CCH * N_PIX;
    const int ib = blockIdx.y;
    const int rg = tid >> 3, pg = tid & 7;
    const int r0 = rg * 5, px0 = pg * 8;
    float acc[5][8] = {};

    for (int c0 = 0; c0 < CCH; c0 += 64) {
        __syncthreads();
        for (int idx = tid; idx < 1024; idx += 256) {
            int c = idx >> 4, q4 = idx & 15;
            float4 v = *(const float4*)&x[(size_t)(c0 + c) * N_PIX + n0 + q4 * 4];
            *(float4*)&xs[c][q4 * 4] = v;
        }
        for (int idx = tid; idx < 2560; idx += 256) {
            int rr = idx >> 4, c4 = idx & 15;
            const float* Wsrc;
            if (rr < 16)      Wsrc = Wq + (size_t)rr * CCH;
            else if (rr < 32) Wsrc = Wk + (size_t)(rr - 16) * CCH;
            else              Wsrc = Wv + (size_t)(rr - 32) * CCH;
            float4 wv = *(const float4*)&Wsrc[c0 + c4 * 4];
            wsm[rr][c4 * 4 + 0] = wv.x; wsm[rr][c4 * 4 + 1] = wv.y;
            wsm[rr][c4 * 4 + 2] = wv.z; wsm[rr][c4 * 4 + 3] = wv.w;
        }
        __syncthreads();
        for (int c = 0; c < 64; ++c) {
            float xv[8];
            float4 xa = *(float4*)&xs[c][px0];
            float4 xb = *(float4*)&xs[c][px0 + 4];
            xv[0] = xa.x; xv[1] = xa.y; xv[2] = xa.z; xv[3] = xa.w;
            xv[4] = xb.x; xv[5] = xb.y; xv[6] = xb.z; xv[7] = xb.w;
            #pragma unroll
            for (int j = 0; j < 5; ++j) {
                float wv = wsm[r0 + j][c];
                #pragma unroll
                for (int p2 = 0; p2 < 8; ++p2) acc[j][p2] += wv * xv[p2];
            }
        }
    }

    #pragma unroll
    for (int j = 0; j < 5; ++j) {
        int rr = r0 + j;
        if (rr < 16) {
            float bias = bq[rr];
            for (int p2 = 0; p2 < 8; ++p2)
                qb[((size_t)ib * N_PIX + n0 + px0 + p2) * 16 + rr] = f2bf(acc[j][p2] + bias);
        } else if (rr < 32) {
            float bias = bk[rr - 16];
            for (int p2 = 0; p2 < 8; ++p2)
                kb[((size_t)ib * N_PIX + n0 + px0 + p2) * 16 + (rr - 16)] = f2bf(acc[j][p2] + bias);
        } else {
            float bias = bv[rr - 32];
            short8 s8;
            for (int p2 = 0; p2 < 8; ++p2) s8[p2] = f2bf(acc[j][p2] + bias);
            *(short8*)&vb[((size_t)ib * DV + (rr - 32)) * N_PIX + n0 + px0] = s8;
        }
    }
}

// ---------------------------------------------------------------------------
// K2: MFMA flash attention, 4-way m-split, atomic partial accumulation.
// grid 1024: r=bid&7 -> pb=r>>1 (XCD pair per problem); inner=(bid>>3)*2+(r&1):
// mh=inner>>6 (m-quarter), n_t=inner&63 (64-row tile). 4 waves/block.
// Single-buffer V LDS with async-split staging (T14); K B-frags direct from
// L2-hot global; per-wave P in LDS. Partials atomicAdd'ed into Pacc/lacc
// (zeroed by memset). 27.6 KB LDS + launch_bounds(256,4) -> 4 blocks/CU.
// ---------------------------------------------------------------------------
__global__ __launch_bounds__(256, 4) void attn_kernel(
    const short* __restrict__ qg, const short* __restrict__ kg,
    const short* __restrict__ vg,
    float* __restrict__ Pacc, float* __restrict__ lacc)
{
    __shared__ short v_lds[128 * 72];     // [c][m], pitch 72 shorts
    __shared__ short p_lds[4][16 * 72];   // per-wave [n][m]

    const int tid = threadIdx.x;
    const int lane = tid & 63;
    const int w = tid >> 6;
    const int B_ = blockIdx.x;
    const int r = B_ & 7;
    const int pb = r >> 1;
    const int inner = (B_ >> 3) * 2 + (r & 1);
    const int mh = inner >> 6;
    const int n0 = (inner & 63) * 64;
    const int br = pb >> 1, b = pb & 1;

    const short* qp = qg + (size_t)pb * N_PIX * 16;
    const short* kp = kg + (size_t)((br ^ 1) * 2 + b) * N_PIX * 16 + (size_t)(mh * 1024) * 16;
    const short* vp = vg + (size_t)pb * DV * N_PIX + mh * 1024;
    float* Pp = Pacc + (size_t)pb * DV * N_PIX;
    float* lp = lacc + (size_t)pb * N_PIX;

    const int g = lane >> 4, l15 = lane & 15;

    // constant Q A-fragment (lanes>=32 zero-pad d 16..31)
    bf16x8 aq = {};
    if (lane < 32)
        aq = *(const bf16x8*)&qp[(size_t)(n0 + w * 16 + l15) * 16 + g * 8];

    f32x4 acc[8];
    #pragma unroll
    for (int cc = 0; cc < 8; ++cc) acc[cc] = (f32x4){0.f, 0.f, 0.f, 0.f};
    float lsum[4] = {0.f, 0.f, 0.f, 0.f};

    const int vc = tid >> 1, vh = tid & 1;   // V staging: row c, 64B half
    int4 vr[4];
    {   // prologue: load chunk 0 into regs
        const int4* gsrc = (const int4*)(vp + (size_t)vc * N_PIX + vh * 32);
        #pragma unroll
        for (int j = 0; j < 4; ++j) vr[j] = gsrc[j];
    }

    for (int t = 0; t < 16; ++t) {
        {   // commit V(t) regs -> LDS
            int4* vd = (int4*)&v_lds[vc * 72 + vh * 32];
            #pragma unroll
            for (int j = 0; j < 4; ++j) vd[j] = vr[j];
        }
        __syncthreads();
        if (t < 15) {   // issue V(t+1) loads; latency hides under compute
            const int4* gsrc = (const int4*)(vp + (size_t)vc * N_PIX + (t + 1) * 64 + vh * 32);
            #pragma unroll
            for (int j = 0; j < 4; ++j) vr[j] = gsrc[j];
        }
        const int m0 = t * 64;
        // QK^T (4 m-halves of 16) -> exp -> P bf16 in per-wave LDS
        #pragma unroll
        for (int h = 0; h < 4; ++h) {
            bf16x8 bk_ = {};
            if (lane < 32)
                bk_ = *(const bf16x8*)&kp[(size_t)(m0 + h * 16 + l15) * 16 + g * 8];
            f32x4 s = __builtin_amdgcn_mfma_f32_16x16x32_bf16(
                aq, bk_, (f32x4){0.f, 0.f, 0.f, 0.f}, 0, 0, 0);
            #pragma unroll
            for (int rr = 0; rr < 4; ++rr) {
                float e = __expf(s[rr] * 0.25f);
                lsum[rr] += e;
                unsigned u = __builtin_bit_cast(unsigned, e);
                p_lds[w][(g * 4 + rr) * 72 + h * 16 + l15] = (short)(u >> 16);
            }
        }
        // PV: O^T[c][n] += V[c][m] * P^T[m][n]
        __builtin_amdgcn_s_setprio(1);
        #pragma unroll
        for (int m2 = 0; m2 < 2; ++m2) {
            bf16x8 bp = *(const bf16x8*)&p_lds[w][l15 * 72 + m2 * 32 + g * 8];
            #pragma unroll
            for (int cc = 0; cc < 8; ++cc) {
                bf16x8 av = *(const bf16x8*)&v_lds[(cc * 16 + l15) * 72 + m2 * 32 + g * 8];
                acc[cc] = __builtin_amdgcn_mfma_f32_16x16x32_bf16(av, bp, acc[cc], 0, 0, 0);
            }
        }
        __builtin_amdgcn_s_setprio(0);
        __syncthreads();   // done reading v_lds before next overwrite
    }

    // reduce l across the 16 m-lanes; atomically accumulate partials
    #pragma unroll
    for (int rr = 0; rr < 4; ++rr) {
        float v = lsum[rr];
        v += __shfl_xor(v, 1); v += __shfl_xor(v, 2);
        v += __shfl_xor(v, 4); v += __shfl_xor(v, 8);
        lsum[rr] = v;
    }
    if (l15 == 0) {
        #pragma unroll
        for (int rr = 0; rr < 4; ++rr)
            atomicAdd(&lp[n0 + w * 16 + g * 4 + rr], lsum[rr]);
    }
    const int n = n0 + w * 16 + l15;
    #pragma unroll
    for (int cc = 0; cc < 8; ++cc) {
        #pragma unroll
        for (int rr = 0; rr < 4; ++rr) {
            int c = cc * 16 + g * 4 + rr;
            atomicAdd(&Pp[(size_t)c * N_PIX + n], acc[cc][rr]);
        }
    }
}

// ---------------------------------------------------------------------------
// K2b: merge + epilogue + prep_s fused.
// out1/out2: c<128 -> gamma*P/l + x_self; c>=128 -> gamma*x_self[c-128]+x_self.
// Also writes s_t[b][px][c] = bf16(out1+out2) (transposed via LDS).
// grid (128, 2): x = 32-px tile, y = b. block 256.
// ---------------------------------------------------------------------------
__global__ __launch_bounds__(256) void merge_kernel(
    const float* __restrict__ x1, const float* __restrict__ x2,
    const float* __restrict__ Pacc, const float* __restrict__ lacc,
    const float* __restrict__ gamma_p,
    float* __restrict__ out1, float* __restrict__ out2,
    short* __restrict__ s_t)
{
    __shared__ short st[32 * 264];
    __shared__ float rls[2][32];
    const int tid = threadIdx.x;
    const int px0 = blockIdx.x * 32;
    const int b = blockIdx.y;
    const float* P0 = Pacc + (size_t)b * DV * N_PIX;        // pb = b   (out1)
    const float* P1 = Pacc + (size_t)(2 + b) * DV * N_PIX;  // pb = 2+b (out2)
    const float* xa_ = x1 + (size_t)b * CCH * N_PIX;
    const float* xb_ = x2 + (size_t)b * CCH * N_PIX;
    float* o1 = out1 + (size_t)b * CCH * N_PIX;
    float* o2 = out2 + (size_t)b * CCH * N_PIX;

    if (tid < 64) {
        int h = tid >> 5, j = tid & 31;
        const float* ls = lacc + (size_t)(h * 2 + b) * N_PIX;
        rls[h][j] = 1.0f / ls[px0 + j];
    }
    __syncthreads();
    const float gmm = gamma_p[0];

    for (int idx = tid; idx < 2048; idx += 256) {   // 256 c x 8 px4
        int c = idx >> 3, p4 = idx & 7;
        size_t off = (size_t)c * N_PIX + px0 + p4 * 4;
        float4 va = *(const float4*)&xa_[off];
        float4 vb2 = *(const float4*)&xb_[off];
        float4 r1, r2;
        if (c < 128) {
            float4 pa = *(const float4*)&P0[off];
            float4 pc = *(const float4*)&P1[off];
            r1.x = gmm * pa.x * rls[0][p4 * 4 + 0] + va.x;
            r1.y = gmm * pa.y * rls[0][p4 * 4 + 1] + va.y;
            r1.z = gmm * pa.z * rls[0][p4 * 4 + 2] + va.z;
            r1.w = gmm * pa.w * rls[0][p4 * 4 + 3] + va.w;
            r2.x = gmm * pc.x * rls[1][p4 * 4 + 0] + vb2.x;
            r2.y = gmm * pc.y * rls[1][p4 * 4 + 1] + vb2.y;
            r2.z = gmm * pc.z * rls[1][p4 * 4 + 2] + vb2.z;
            r2.w = gmm * pc.w * rls[1][p4 * 4 + 3] + vb2.w;
        } else {
            size_t offl = (size_t)(c - 128) * N_PIX + px0 + p4 * 4;
            float4 val = *(const float4*)&xa_[offl];
            float4 vbl = *(const float4*)&xb_[offl];
            r1.x = gmm * val.x + va.x; r1.y = gmm * val.y + va.y;
            r1.z = gmm * val.z + va.z; r1.w = gmm * val.w + va.w;
            r2.x = gmm * vbl.x + vb2.x; r2.y = gmm * vbl.y + vb2.y;
            r2.z = gmm * vbl.z + vb2.z; r2.w = gmm * vbl.w + vb2.w;
        }
        *(float4*)&o1[off] = r1;
        *(float4*)&o2[off] = r2;
        st[(p4 * 4 + 0) * 264 + c] = f2bf(r1.x + r2.x);
        st[(p4 * 4 + 1) * 264 + c] = f2bf(r1.y + r2.y);
        st[(p4 * 4 + 2) * 264 + c] = f2bf(r1.z + r2.z);
        st[(p4 * 4 + 3) * 264 + c] = f2bf(r1.w + r2.w);
    }
    __syncthreads();
    for (int idx = tid; idx < 1024; idx += 256) {   // 32 px x 32 seg
        int px = idx >> 5, seg = idx & 31;
        int4 v = *(const int4*)&st[px * 264 + seg * 8];
        *(int4*)&s_t[((size_t)b * N_PIX + px0 + px) * CCH + seg * 8] = v;
    }
}

// ---------------------------------------------------------------------------
// K3b: prep_w — Wcat fp32 [oc][ic][3][3] -> bf16 A-fragment order
// ---------------------------------------------------------------------------
__global__ __launch_bounds__(256) void prep_w(
    const float* __restrict__ Wcat, short* __restrict__ wfmt)
{
    int idx = blockIdx.x * 256 + threadIdx.x;
    int lane = idx & 63;
    int ocg = (idx >> 6) & 15;
    int chunk = (idx >> 10) & 7;
    int tap = idx >> 13;
    int oc = ocg * 16 + (lane & 15);
    int ic0 = chunk * 32 + (lane >> 4) * 8;
    short8 v;
    #pragma unroll
    for (int j = 0; j < 8; ++j)
        v[j] = f2bf(Wcat[((size_t)oc * CCH + ic0 + j) * 9 + tap]);
    *(short8*)&wfmt[(size_t)idx * 8] = v;
}

// ---------------------------------------------------------------------------
// K3c: conv as implicit GEMM on MFMA (unchanged)
// ---------------------------------------------------------------------------
__global__ __launch_bounds__(256) void conv_mfma(
    const short* __restrict__ s_t, const short* __restrict__ wfmt,
    const float* __restrict__ bn_gamma, const float* __restrict__ bn_beta,
    float* __restrict__ feat)
{
    __shared__ short s_lds[264 * 40];
    const int tid = threadIdx.x;
    const int lane = tid & 63;
    const int wv = tid >> 6;
    const int g = lane >> 4, l15 = lane & 15;

    const int bx = blockIdx.x;
    const int oc_t = bx & 3;
    const int pt = bx >> 2;
    const int b = pt >> 5;
    const int h0 = (pt & 31) * 2;

    f32x4 acc[2][4] = {};

    const short* sbase = s_t + (size_t)b * N_PIX * CCH;
    const short* wf = wfmt + ((size_t)(oc_t * 4) * 64 + lane) * 8;

    for (int ci = 0; ci < 8; ++ci) {
        const int ic0 = ci * 32;
        __syncthreads();
        for (int idx = tid; idx < 1056; idx += 256) {
            int seg = idx & 3, pos = idx >> 2;
            int row = pos / 66, wi = pos - row * 66;
            int hr = h0 - 1 + row, w = wi - 1;
            int4 val = {0, 0, 0, 0};
            if (hr >= 0 && hr < 64 && (unsigned)w < 64u)
                val = *(const int4*)&sbase[((size_t)(hr * 64 + w)) * CCH + ic0 + seg * 8];
            *(int4*)&s_lds[pos * 40 + seg * 8] = val;
        }
        __syncthreads();

        const short* wfc = wf + (size_t)ci * 8192;
        bf16x8 a0[4], a1[4];
        #pragma unroll
        for (int j = 0; j < 4; ++j) a0[j] = *(const bf16x8*)&wfc[j * 512];

        for (int tap = 0; tap < 9; ++tap) {
            bf16x8* ac = (tap & 1) ? a1 : a0;
            bf16x8* an = (tap & 1) ? a0 : a1;
            if (tap < 8) {
                const short* wfn = wfc + (size_t)(tap + 1) * 65536;
                #pragma unroll
                for (int j = 0; j < 4; ++j) an[j] = *(const bf16x8*)&wfn[j * 512];
            }
            int ky = (tap >= 6) ? 2 : (tap >= 3 ? 1 : 0);
            int kx = tap - ky * 3;
            #pragma unroll
            for (int f = 0; f < 2; ++f) {
                int fr = wv * 2 + f;
                int rl = fr >> 2, wc0 = (fr & 3) * 16;
                bf16x8 bb = *(const bf16x8*)
                    &s_lds[((rl + ky) * 66 + wc0 + l15 + kx) * 40 + g * 8];
                #pragma unroll
                for (int j = 0; j < 4; ++j)
                    acc[f][j] = __builtin_amdgcn_mfma_f32_16x16x32_bf16(
                        ac[j], bb, acc[f][j], 0, 0, 0);
            }
        }
    }

    const float inv = rsqrtf(1.0f + 1e-5f);
    #pragma unroll
    for (int f = 0; f < 2; ++f) {
        int fr = wv * 2 + f;
        int rl = fr >> 2, wc0 = (fr & 3) * 16;
        int h = h0 + rl, wcol = wc0 + l15;
        #pragma unroll
        for (int j = 0; j < 4; ++j) {
            #pragma unroll
            for (int r = 0; r < 4; ++r) {
                int oc = oc_t * 64 + j * 16 + g * 4 + r;
                float y = acc[f][j][r] * (bn_gamma[oc] * inv) + bn_beta[oc];
                feat[((size_t)b * CCH + oc) * N_PIX + h * 64 + wcol] = fmaxf(y, 0.f);
            }
        }
    }
}

// ---------------------------------------------------------------------------
extern "C" void kernel_launch(void* const* d_in, const int* in_sizes, int n_in,
                              void* d_out, int out_size, void* d_ws, size_t ws_size,
                              hipStream_t stream) {
    const float* x1    = (const float*)d_in[0];
    const float* x2    = (const float*)d_in[1];
    const float* Wq    = (const float*)d_in[2];
    const float* bq    = (const float*)d_in[3];
    const float* Wk    = (const float*)d_in[4];
    const float* bk    = (const float*)d_in[5];
    const float* Wv    = (const float*)d_in[6];
    const float* bv    = (const float*)d_in[7];
    const float* gamma = (const float*)d_in[8];
    const float* Wcat  = (const float*)d_in[9];
    const float* bng   = (const float*)d_in[10];
    const float* bnb   = (const float*)d_in[11];

    float* out  = (float*)d_out;
    float* feat = out;                    // also hosts attn partials (zeroed)
    float* out1 = out + 2097152;
    float* out2 = out + 4194304;

    short* ws   = (short*)d_ws;
    short* qb   = ws;                     // 262144 shorts
    short* kb   = ws + 262144;            // 262144
    short* vb   = ws + 524288;            // 2097152
    short* s_t  = ws + 2621440;           // 2097152
    short* wfmt = ws + 4718592;           // 589824
    float* lp   = (float*)(ws + 5308416); // 4*4096 f32 l-accumulator

    hipMemsetAsync(feat, 0, (size_t)2097152 * sizeof(float), stream);
    hipMemsetAsync(lp, 0, (size_t)4 * N_PIX * sizeof(float), stream);
    prep_w<<<288, 256, 0, stream>>>(Wcat, wfmt);
    qkv_kernel<<<dim3(64, 4), 256, 0, stream>>>(x1, x2, Wq, bq, Wk, bk, Wv, bv, qb, kb, vb);
    attn_kernel<<<1024, 256, 0, stream>>>(qb, kb, vb, feat, lp);
    merge_kernel<<<dim3(128, 2), 256, 0, stream>>>(x1, x2, feat, lp, gamma, out1, out2, s_t);
    conv_mfma<<<256, 256, 0, stream>>>(s_t, wfmt, bng, bnb, feat);
}

// Round 7
// 178.014 us; speedup vs baseline: 1.1197x; 1.1197x over previous
//
#include <hip/hip_runtime.h>

#define N_PIX 4096
#define CCH 256
#define DV 128

typedef __attribute__((ext_vector_type(8))) short bf16x8;
typedef __attribute__((ext_vector_type(4))) float f32x4;
typedef __attribute__((ext_vector_type(8))) short short8;

__device__ __forceinline__ short f2bf(float f) {
    unsigned u = __builtin_bit_cast(unsigned, f);
    u += 0x7fffu + ((u >> 16) & 1u);
    return (short)(u >> 16);
}

__device__ __forceinline__ float4 bf4_load(const short* p) {
    short4 s = *(const short4*)p;
    float4 f;
    f.x = __builtin_bit_cast(float, (unsigned)((unsigned short)s.x) << 16);
    f.y = __builtin_bit_cast(float, (unsigned)((unsigned short)s.y) << 16);
    f.z = __builtin_bit_cast(float, (unsigned)((unsigned short)s.z) << 16);
    f.w = __builtin_bit_cast(float, (unsigned)((unsigned short)s.w) << 16);
    return f;
}

// ---------------------------------------------------------------------------
// K1: fused 1x1 convs (register-tiled fp32 GEMM, W staged in LDS) ->
//     qb[ib][n][16] bf16, kb[ib][n][16] bf16, vb[ib][c][N] bf16
// ---------------------------------------------------------------------------
__global__ __launch_bounds__(256) void qkv_kernel(
    const float* __restrict__ x1, const float* __restrict__ x2,
    const float* __restrict__ Wq, const float* __restrict__ bq,
    const float* __restrict__ Wk, const float* __restrict__ bk,
    const float* __restrict__ Wv, const float* __restrict__ bv,
    short* __restrict__ qb, short* __restrict__ kb, short* __restrict__ vb)
{
    __shared__ float xs[64][64];
    __shared__ float wsm[160][65];
    const int tid = threadIdx.x;
    const int n0 = blockIdx.x * 64;
    const int i = blockIdx.y >> 1, b = blockIdx.y & 1;
    const float* x = (i == 0 ? x1 : x2) + (size_t)b * CCH * N_PIX;
    const int ib = blockIdx.y;
    const int rg = tid >> 3, pg = tid & 7;
    const int r0 = rg * 5, px0 = pg * 8;
    float acc[5][8] = {};

    for (int c0 = 0; c0 < CCH; c0 += 64) {
        __syncthreads();
        for (int idx = tid; idx < 1024; idx += 256) {
            int c = idx >> 4, q4 = idx & 15;
            float4 v = *(const float4*)&x[(size_t)(c0 + c) * N_PIX + n0 + q4 * 4];
            *(float4*)&xs[c][q4 * 4] = v;
        }
        for (int idx = tid; idx < 2560; idx += 256) {
            int rr = idx >> 4, c4 = idx & 15;
            const float* Wsrc;
            if (rr < 16)      Wsrc = Wq + (size_t)rr * CCH;
            else if (rr < 32) Wsrc = Wk + (size_t)(rr - 16) * CCH;
            else              Wsrc = Wv + (size_t)(rr - 32) * CCH;
            float4 wv = *(const float4*)&Wsrc[c0 + c4 * 4];
            wsm[rr][c4 * 4 + 0] = wv.x; wsm[rr][c4 * 4 + 1] = wv.y;
            wsm[rr][c4 * 4 + 2] = wv.z; wsm[rr][c4 * 4 + 3] = wv.w;
        }
        __syncthreads();
        for (int c = 0; c < 64; ++c) {
            float xv[8];
            float4 xa = *(float4*)&xs[c][px0];
            float4 xb = *(float4*)&xs[c][px0 + 4];
            xv[0] = xa.x; xv[1] = xa.y; xv[2] = xa.z; xv[3] = xa.w;
            xv[4] = xb.x; xv[5] = xb.y; xv[6] = xb.z; xv[7] = xb.w;
            #pragma unroll
            for (int j = 0; j < 5; ++j) {
                float wv = wsm[r0 + j][c];
                #pragma unroll
                for (int p2 = 0; p2 < 8; ++p2) acc[j][p2] += wv * xv[p2];
            }
        }
    }

    #pragma unroll
    for (int j = 0; j < 5; ++j) {
        int rr = r0 + j;
        if (rr < 16) {
            float bias = bq[rr];
            for (int p2 = 0; p2 < 8; ++p2)
                qb[((size_t)ib * N_PIX + n0 + px0 + p2) * 16 + rr] = f2bf(acc[j][p2] + bias);
        } else if (rr < 32) {
            float bias = bk[rr - 16];
            for (int p2 = 0; p2 < 8; ++p2)
                kb[((size_t)ib * N_PIX + n0 + px0 + p2) * 16 + (rr - 16)] = f2bf(acc[j][p2] + bias);
        } else {
            float bias = bv[rr - 32];
            short8 s8;
            for (int p2 = 0; p2 < 8; ++p2) s8[p2] = f2bf(acc[j][p2] + bias);
            *(short8*)&vb[((size_t)ib * DV + (rr - 32)) * N_PIX + n0 + px0] = s8;
        }
    }
}

// ---------------------------------------------------------------------------
// K2: MFMA flash attention, 3-way m-split, NO atomics.
// grid 768: pb = bid&3, mh = (bid>>2)%3, nt = bid/12 (64-row n-tile).
// 4 waves/block; K+V staged via regs->LDS (single buffer, async-split T14);
// per-wave P in LDS. m-chunks [tstart,tend) of 64: {0..22,22..43,43..64}.
// Partials: mh=0 -> f32 at final out1/out2 c<128 slots (merged in-place);
//           mh=1,2 -> bf16 slots in feat region. l -> lpart[pb*3+mh].
// LDS 30.7KB, launch_bounds(256,3) -> 3 blocks/CU (12 waves).
// ---------------------------------------------------------------------------
__global__ __launch_bounds__(256, 3) void attn_kernel(
    const short* __restrict__ qg, const short* __restrict__ kg,
    const short* __restrict__ vg,
    float* __restrict__ out1, float* __restrict__ out2,
    short* __restrict__ featp, float* __restrict__ lpart)
{
    __shared__ short k_lds[64 * 24];      // [m][d], pitch 24 shorts
    __shared__ short v_lds[128 * 72];     // [c][m], pitch 72 shorts
    __shared__ short p_lds[4][16 * 72];   // per-wave [n][m]

    const int tid = threadIdx.x;
    const int lane = tid & 63;
    const int w = tid >> 6;
    const int B_ = blockIdx.x;
    const int pb = B_ & 3;
    const int mh = (B_ >> 2) % 3;
    const int n0 = (B_ / 12) * 64;
    const int br = pb >> 1, b = pb & 1;
    const int tstart = (mh == 0) ? 0 : (mh == 1 ? 22 : 43);
    const int tend   = (mh == 0) ? 22 : (mh == 1 ? 43 : 64);

    const short* qp = qg + (size_t)pb * N_PIX * 16;
    const short* kp = kg + (size_t)((br ^ 1) * 2 + b) * N_PIX * 16;
    const short* vp = vg + (size_t)pb * DV * N_PIX;

    const int g = lane >> 4, l15 = lane & 15;

    // constant Q A-fragment (lanes>=32 zero-pad d 16..31)
    bf16x8 aq = {};
    if (lane < 32)
        aq = *(const bf16x8*)&qp[(size_t)(n0 + w * 16 + l15) * 16 + g * 8];

    f32x4 acc[8];
    #pragma unroll
    for (int cc = 0; cc < 8; ++cc) acc[cc] = (f32x4){0.f, 0.f, 0.f, 0.f};
    float lsum[4] = {0.f, 0.f, 0.f, 0.f};

    const int vc = tid >> 1, vh = tid & 1;   // V staging: row c, 64B half
    const int krow = tid - 192;              // K staging: threads 192..255

    int4 vr[4]; int4 kr0 = {}, kr1 = {};
    {   // prologue: load chunk tstart into regs
        const int4* gsrc = (const int4*)(vp + (size_t)vc * N_PIX + tstart * 64 + vh * 32);
        #pragma unroll
        for (int j = 0; j < 4; ++j) vr[j] = gsrc[j];
        if (tid >= 192) {
            kr0 = *(const int4*)&kp[(size_t)(tstart * 64 + krow) * 16];
            kr1 = *(const int4*)&kp[(size_t)(tstart * 64 + krow) * 16 + 8];
        }
    }

    for (int t = tstart; t < tend; ++t) {
        {   // commit chunk t regs -> LDS
            int4* vd = (int4*)&v_lds[vc * 72 + vh * 32];
            #pragma unroll
            for (int j = 0; j < 4; ++j) vd[j] = vr[j];
            if (tid >= 192) {
                *(int4*)&k_lds[krow * 24] = kr0;
                *(int4*)&k_lds[krow * 24 + 8] = kr1;
            }
        }
        __syncthreads();
        if (t + 1 < tend) {   // issue chunk t+1 loads; latency hides under compute
            const int4* gsrc = (const int4*)(vp + (size_t)vc * N_PIX + (t + 1) * 64 + vh * 32);
            #pragma unroll
            for (int j = 0; j < 4; ++j) vr[j] = gsrc[j];
            if (tid >= 192) {
                kr0 = *(const int4*)&kp[(size_t)((t + 1) * 64 + krow) * 16];
                kr1 = *(const int4*)&kp[(size_t)((t + 1) * 64 + krow) * 16 + 8];
            }
        }
        // QK^T (4 m-halves of 16) -> exp -> P bf16 (trunc) in per-wave LDS
        #pragma unroll
        for (int h = 0; h < 4; ++h) {
            bf16x8 bk_ = {};
            if (lane < 32)
                bk_ = *(const bf16x8*)&k_lds[(h * 16 + l15) * 24 + g * 8];
            f32x4 s = __builtin_amdgcn_mfma_f32_16x16x32_bf16(
                aq, bk_, (f32x4){0.f, 0.f, 0.f, 0.f}, 0, 0, 0);
            #pragma unroll
            for (int rr = 0; rr < 4; ++rr) {
                float e = __expf(s[rr] * 0.25f);
                lsum[rr] += e;
                unsigned u = __builtin_bit_cast(unsigned, e);
                p_lds[w][(g * 4 + rr) * 72 + h * 16 + l15] = (short)(u >> 16);
            }
        }
        // PV: O^T[c][n] += V[c][m] * P^T[m][n]
        __builtin_amdgcn_s_setprio(1);
        #pragma unroll
        for (int m2 = 0; m2 < 2; ++m2) {
            bf16x8 bp = *(const bf16x8*)&p_lds[w][l15 * 72 + m2 * 32 + g * 8];
            #pragma unroll
            for (int cc = 0; cc < 8; ++cc) {
                bf16x8 av = *(const bf16x8*)&v_lds[(cc * 16 + l15) * 72 + m2 * 32 + g * 8];
                acc[cc] = __builtin_amdgcn_mfma_f32_16x16x32_bf16(av, bp, acc[cc], 0, 0, 0);
            }
        }
        __builtin_amdgcn_s_setprio(0);
        __syncthreads();   // all reads of LDS done before next commit
    }

    // reduce l across the 16 m-lanes; store partial sums (no atomics)
    #pragma unroll
    for (int rr = 0; rr < 4; ++rr) {
        float v = lsum[rr];
        v += __shfl_xor(v, 1); v += __shfl_xor(v, 2);
        v += __shfl_xor(v, 4); v += __shfl_xor(v, 8);
        lsum[rr] = v;
    }
    if (l15 == 0) {
        #pragma unroll
        for (int rr = 0; rr < 4; ++rr)
            lpart[(size_t)(pb * 3 + mh) * N_PIX + n0 + w * 16 + g * 4 + rr] = lsum[rr];
    }

    const int n = n0 + w * 16 + l15;
    if (mh == 0) {   // f32 partial directly at final location (c<128 slots)
        float* Od = (br ? out2 : out1) + (size_t)b * CCH * N_PIX;
        #pragma unroll
        for (int cc = 0; cc < 8; ++cc) {
            #pragma unroll
            for (int rr = 0; rr < 4; ++rr) {
                int c = cc * 16 + g * 4 + rr;
                Od[(size_t)c * N_PIX + n] = acc[cc][rr];
            }
        }
    } else {         // bf16 partial slot in feat region
        short* Ps = featp + (size_t)(pb * 2 + (mh - 1)) * (DV * N_PIX);
        #pragma unroll
        for (int cc = 0; cc < 8; ++cc) {
            #pragma unroll
            for (int rr = 0; rr < 4; ++rr) {
                int c = cc * 16 + g * 4 + rr;
                Ps[(size_t)c * N_PIX + n] = f2bf(acc[cc][rr]);
            }
        }
    }
}

// ---------------------------------------------------------------------------
// K2b: merge 3 partials + epilogue + prep_s fused.
// out1/out2: c<128 -> gamma*(P0+P1+P2)/(l0+l1+l2) + x_self;
//            c>=128 -> gamma*x_self[c-128] + x_self.
// Also writes s_t[b][px][c] = bf16(out1+out2). grid (128,2), block 256.
// ---------------------------------------------------------------------------
__global__ __launch_bounds__(256) void merge_kernel(
    const float* __restrict__ x1, const float* __restrict__ x2,
    const short* __restrict__ featp, const float* __restrict__ lpart,
    const float* __restrict__ gamma_p,
    float* __restrict__ out1, float* __restrict__ out2,
    short* __restrict__ s_t)
{
    __shared__ short st[32 * 264];
    __shared__ float rls[2][32];
    const int tid = threadIdx.x;
    const int px0 = blockIdx.x * 32;
    const int b = blockIdx.y;
    const float* xa_ = x1 + (size_t)b * CCH * N_PIX;
    const float* xb_ = x2 + (size_t)b * CCH * N_PIX;
    float* o1 = out1 + (size_t)b * CCH * N_PIX;   // pb = b     (holds mh=0 f32 partial, c<128)
    float* o2 = out2 + (size_t)b * CCH * N_PIX;   // pb = 2 + b
    const short* B10 = featp + (size_t)(b * 2 + 0) * (DV * N_PIX);        // pb=b   mh=1
    const short* B11 = featp + (size_t)(b * 2 + 1) * (DV * N_PIX);        // pb=b   mh=2
    const short* B20 = featp + (size_t)((2 + b) * 2 + 0) * (DV * N_PIX);  // pb=2+b mh=1
    const short* B21 = featp + (size_t)((2 + b) * 2 + 1) * (DV * N_PIX);  // pb=2+b mh=2

    if (tid < 64) {
        int h = tid >> 5, j = tid & 31;
        int pbh = h ? (2 + b) : b;
        float l = lpart[(size_t)(pbh * 3 + 0) * N_PIX + px0 + j]
                + lpart[(size_t)(pbh * 3 + 1) * N_PIX + px0 + j]
                + lpart[(size_t)(pbh * 3 + 2) * N_PIX + px0 + j];
        rls[h][j] = 1.0f / l;
    }
    __syncthreads();
    const float gmm = gamma_p[0];

    for (int idx = tid; idx < 2048; idx += 256) {   // 256 c x 8 px4
        int c = idx >> 3, p4 = idx & 7;
        size_t off = (size_t)c * N_PIX + px0 + p4 * 4;
        float4 va = *(const float4*)&xa_[off];
        float4 vb2 = *(const float4*)&xb_[off];
        float4 r1, r2;
        if (c < 128) {
            size_t boff = (size_t)c * N_PIX + px0 + p4 * 4;
            float4 pa = *(const float4*)&o1[off];
            float4 pc = *(const float4*)&o2[off];
            float4 a1 = bf4_load(&B10[boff]);
            float4 a2 = bf4_load(&B11[boff]);
            float4 c1 = bf4_load(&B20[boff]);
            float4 c2 = bf4_load(&B21[boff]);
            r1.x = gmm * (pa.x + a1.x + a2.x) * rls[0][p4 * 4 + 0] + va.x;
            r1.y = gmm * (pa.y + a1.y + a2.y) * rls[0][p4 * 4 + 1] + va.y;
            r1.z = gmm * (pa.z + a1.z + a2.z) * rls[0][p4 * 4 + 2] + va.z;
            r1.w = gmm * (pa.w + a1.w + a2.w) * rls[0][p4 * 4 + 3] + va.w;
            r2.x = gmm * (pc.x + c1.x + c2.x) * rls[1][p4 * 4 + 0] + vb2.x;
            r2.y = gmm * (pc.y + c1.y + c2.y) * rls[1][p4 * 4 + 1] + vb2.y;
            r2.z = gmm * (pc.z + c1.z + c2.z) * rls[1][p4 * 4 + 2] + vb2.z;
            r2.w = gmm * (pc.w + c1.w + c2.w) * rls[1][p4 * 4 + 3] + vb2.w;
        } else {
            size_t offl = (size_t)(c - 128) * N_PIX + px0 + p4 * 4;
            float4 val = *(const float4*)&xa_[offl];
            float4 vbl = *(const float4*)&xb_[offl];
            r1.x = gmm * val.x + va.x; r1.y = gmm * val.y + va.y;
            r1.z = gmm * val.z + va.z; r1.w = gmm * val.w + va.w;
            r2.x = gmm * vbl.x + vb2.x; r2.y = gmm * vbl.y + vb2.y;
            r2.z = gmm * vbl.z + vb2.z; r2.w = gmm * vbl.w + vb2.w;
        }
        *(float4*)&o1[off] = r1;
        *(float4*)&o2[off] = r2;
        st[(p4 * 4 + 0) * 264 + c] = f2bf(r1.x + r2.x);
        st[(p4 * 4 + 1) * 264 + c] = f2bf(r1.y + r2.y);
        st[(p4 * 4 + 2) * 264 + c] = f2bf(r1.z + r2.z);
        st[(p4 * 4 + 3) * 264 + c] = f2bf(r1.w + r2.w);
    }
    __syncthreads();
    for (int idx = tid; idx < 1024; idx += 256) {   // 32 px x 32 seg
        int px = idx >> 5, seg = idx & 31;
        int4 v = *(const int4*)&st[px * 264 + seg * 8];
        *(int4*)&s_t[((size_t)b * N_PIX + px0 + px) * CCH + seg * 8] = v;
    }
}

// ---------------------------------------------------------------------------
// K3b: prep_w — Wcat fp32 [oc][ic][3][3] -> bf16 A-fragment order
// ---------------------------------------------------------------------------
__global__ __launch_bounds__(256) void prep_w(
    const float* __restrict__ Wcat, short* __restrict__ wfmt)
{
    int idx = blockIdx.x * 256 + threadIdx.x;
    int lane = idx & 63;
    int ocg = (idx >> 6) & 15;
    int chunk = (idx >> 10) & 7;
    int tap = idx >> 13;
    int oc = ocg * 16 + (lane & 15);
    int ic0 = chunk * 32 + (lane >> 4) * 8;
    short8 v;
    #pragma unroll
    for (int j = 0; j < 8; ++j)
        v[j] = f2bf(Wcat[((size_t)oc * CCH + ic0 + j) * 9 + tap]);
    *(short8*)&wfmt[(size_t)idx * 8] = v;
}

// ---------------------------------------------------------------------------
// K3c: conv as implicit GEMM on MFMA (unchanged)
// ---------------------------------------------------------------------------
__global__ __launch_bounds__(256) void conv_mfma(
    const short* __restrict__ s_t, const short* __restrict__ wfmt,
    const float* __restrict__ bn_gamma, const float* __restrict__ bn_beta,
    float* __restrict__ feat)
{
    __shared__ short s_lds[264 * 40];
    const int tid = threadIdx.x;
    const int lane = tid & 63;
    const int wv = tid >> 6;
    const int g = lane >> 4, l15 = lane & 15;

    const int bx = blockIdx.x;
    const int oc_t = bx & 3;
    const int pt = bx >> 2;
    const int b = pt >> 5;
    const int h0 = (pt & 31) * 2;

    f32x4 acc[2][4] = {};

    const short* sbase = s_t + (size_t)b * N_PIX * CCH;
    const short* wf = wfmt + ((size_t)(oc_t * 4) * 64 + lane) * 8;

    for (int ci = 0; ci < 8; ++ci) {
        const int ic0 = ci * 32;
        __syncthreads();
        for (int idx = tid; idx < 1056; idx += 256) {
            int seg = idx & 3, pos = idx >> 2;
            int row = pos / 66, wi = pos - row * 66;
            int hr = h0 - 1 + row, w = wi - 1;
            int4 val = {0, 0, 0, 0};
            if (hr >= 0 && hr < 64 && (unsigned)w < 64u)
                val = *(const int4*)&sbase[((size_t)(hr * 64 + w)) * CCH + ic0 + seg * 8];
            *(int4*)&s_lds[pos * 40 + seg * 8] = val;
        }
        __syncthreads();

        const short* wfc = wf + (size_t)ci * 8192;
        bf16x8 a0[4], a1[4];
        #pragma unroll
        for (int j = 0; j < 4; ++j) a0[j] = *(const bf16x8*)&wfc[j * 512];

        for (int tap = 0; tap < 9; ++tap) {
            bf16x8* ac = (tap & 1) ? a1 : a0;
            bf16x8* an = (tap & 1) ? a0 : a1;
            if (tap < 8) {
                const short* wfn = wfc + (size_t)(tap + 1) * 65536;
                #pragma unroll
                for (int j = 0; j < 4; ++j) an[j] = *(const bf16x8*)&wfn[j * 512];
            }
            int ky = (tap >= 6) ? 2 : (tap >= 3 ? 1 : 0);
            int kx = tap - ky * 3;
            #pragma unroll
            for (int f = 0; f < 2; ++f) {
                int fr = wv * 2 + f;
                int rl = fr >> 2, wc0 = (fr & 3) * 16;
                bf16x8 bb = *(const bf16x8*)
                    &s_lds[((rl + ky) * 66 + wc0 + l15 + kx) * 40 + g * 8];
                #pragma unroll
                for (int j = 0; j < 4; ++j)
                    acc[f][j] = __builtin_amdgcn_mfma_f32_16x16x32_bf16(
                        ac[j], bb, acc[f][j], 0, 0, 0);
            }
        }
    }

    const float inv = rsqrtf(1.0f + 1e-5f);
    #pragma unroll
    for (int f = 0; f < 2; ++f) {
        int fr = wv * 2 + f;
        int rl = fr >> 2, wc0 = (fr & 3) * 16;
        int h = h0 + rl, wcol = wc0 + l15;
        #pragma unroll
        for (int j = 0; j < 4; ++j) {
            #pragma unroll
            for (int r = 0; r < 4; ++r) {
                int oc = oc_t * 64 + j * 16 + g * 4 + r;
                float y = acc[f][j][r] * (bn_gamma[oc] * inv) + bn_beta[oc];
                feat[((size_t)b * CCH + oc) * N_PIX + h * 64 + wcol] = fmaxf(y, 0.f);
            }
        }
    }
}

// ---------------------------------------------------------------------------
extern "C" void kernel_launch(void* const* d_in, const int* in_sizes, int n_in,
                              void* d_out, int out_size, void* d_ws, size_t ws_size,
                              hipStream_t stream) {
    const float* x1    = (const float*)d_in[0];
    const float* x2    = (const float*)d_in[1];
    const float* Wq    = (const float*)d_in[2];
    const float* bq    = (const float*)d_in[3];
    const float* Wk    = (const float*)d_in[4];
    const float* bk    = (const float*)d_in[5];
    const float* Wv    = (const float*)d_in[6];
    const float* bv    = (const float*)d_in[7];
    const float* gamma = (const float*)d_in[8];
    const float* Wcat  = (const float*)d_in[9];
    const float* bng   = (const float*)d_in[10];
    const float* bnb   = (const float*)d_in[11];

    float* out  = (float*)d_out;
    float* feat = out;                    // hosts 8 bf16 partial slots pre-conv
    float* out1 = out + 2097152;
    float* out2 = out + 4194304;

    short* ws   = (short*)d_ws;
    short* qb   = ws;                     // 262144 shorts
    short* kb   = ws + 262144;            // 262144
    short* vb   = ws + 524288;            // 2097152
    short* s_t  = ws + 2621440;           // 2097152
    short* wfmt = ws + 4718592;           // 589824
    float* lp   = (float*)(ws + 5308416); // 12*4096 f32 l-partials

    prep_w<<<288, 256, 0, stream>>>(Wcat, wfmt);
    qkv_kernel<<<dim3(64, 4), 256, 0, stream>>>(x1, x2, Wq, bq, Wk, bk, Wv, bv, qb, kb, vb);
    attn_kernel<<<768, 256, 0, stream>>>(qb, kb, vb, out1, out2, (short*)feat, lp);
    merge_kernel<<<dim3(128, 2), 256, 0, stream>>>(x1, x2, (const short*)feat, lp, gamma, out1, out2, s_t);
    conv_mfma<<<256, 256, 0, stream>>>(s_t, wfmt, bng, bnb, feat);
}

// Round 8
// 134.572 us; speedup vs baseline: 1.4811x; 1.3228x over previous
//
#include <hip/hip_runtime.h>

#define N_PIX 4096
#define CCH 256
#define DV 128

typedef __attribute__((ext_vector_type(8))) short bf16x8;
typedef __attribute__((ext_vector_type(4))) float f32x4;
typedef __attribute__((ext_vector_type(8))) short short8;

__device__ __forceinline__ short f2bf(float f) {
    unsigned u = __builtin_bit_cast(unsigned, f);
    u += 0x7fffu + ((u >> 16) & 1u);
    return (short)(u >> 16);
}

// ---------------------------------------------------------------------------
// K1: fused 1x1 convs (register-tiled fp32 GEMM, W staged in LDS) ->
//     qb[ib][n][16] bf16, kb[ib][n][16] bf16, vb[ib][c][N] bf16
// ---------------------------------------------------------------------------
__global__ __launch_bounds__(256) void qkv_kernel(
    const float* __restrict__ x1, const float* __restrict__ x2,
    const float* __restrict__ Wq, const float* __restrict__ bq,
    const float* __restrict__ Wk, const float* __restrict__ bk,
    const float* __restrict__ Wv, const float* __restrict__ bv,
    short* __restrict__ qb, short* __restrict__ kb, short* __restrict__ vb)
{
    __shared__ float xs[64][64];
    __shared__ float wsm[160][65];
    const int tid = threadIdx.x;
    const int n0 = blockIdx.x * 64;
    const int i = blockIdx.y >> 1, b = blockIdx.y & 1;
    const float* x = (i == 0 ? x1 : x2) + (size_t)b * CCH * N_PIX;
    const int ib = blockIdx.y;
    const int rg = tid >> 3, pg = tid & 7;
    const int r0 = rg * 5, px0 = pg * 8;
    float acc[5][8] = {};

    for (int c0 = 0; c0 < CCH; c0 += 64) {
        __syncthreads();
        for (int idx = tid; idx < 1024; idx += 256) {
            int c = idx >> 4, q4 = idx & 15;
            float4 v = *(const float4*)&x[(size_t)(c0 + c) * N_PIX + n0 + q4 * 4];
            *(float4*)&xs[c][q4 * 4] = v;
        }
        for (int idx = tid; idx < 2560; idx += 256) {
            int rr = idx >> 4, c4 = idx & 15;
            const float* Wsrc;
            if (rr < 16)      Wsrc = Wq + (size_t)rr * CCH;
            else if (rr < 32) Wsrc = Wk + (size_t)(rr - 16) * CCH;
            else              Wsrc = Wv + (size_t)(rr - 32) * CCH;
            float4 wv = *(const float4*)&Wsrc[c0 + c4 * 4];
            wsm[rr][c4 * 4 + 0] = wv.x; wsm[rr][c4 * 4 + 1] = wv.y;
            wsm[rr][c4 * 4 + 2] = wv.z; wsm[rr][c4 * 4 + 3] = wv.w;
        }
        __syncthreads();
        for (int c = 0; c < 64; ++c) {
            float xv[8];
            float4 xa = *(float4*)&xs[c][px0];
            float4 xb = *(float4*)&xs[c][px0 + 4];
            xv[0] = xa.x; xv[1] = xa.y; xv[2] = xa.z; xv[3] = xa.w;
            xv[4] = xb.x; xv[5] = xb.y; xv[6] = xb.z; xv[7] = xb.w;
            #pragma unroll
            for (int j = 0; j < 5; ++j) {
                float wv = wsm[r0 + j][c];
                #pragma unroll
                for (int p2 = 0; p2 < 8; ++p2) acc[j][p2] += wv * xv[p2];
            }
        }
    }

    #pragma unroll
    for (int j = 0; j < 5; ++j) {
        int rr = r0 + j;
        if (rr < 16) {
            float bias = bq[rr];
            for (int p2 = 0; p2 < 8; ++p2)
                qb[((size_t)ib * N_PIX + n0 + px0 + p2) * 16 + rr] = f2bf(acc[j][p2] + bias);
        } else if (rr < 32) {
            float bias = bk[rr - 16];
            for (int p2 = 0; p2 < 8; ++p2)
                kb[((size_t)ib * N_PIX + n0 + px0 + p2) * 16 + (rr - 16)] = f2bf(acc[j][p2] + bias);
        } else {
            float bias = bv[rr - 32];
            short8 s8;
            for (int p2 = 0; p2 < 8; ++p2) s8[p2] = f2bf(acc[j][p2] + bias);
            *(short8*)&vb[((size_t)ib * DV + (rr - 32)) * N_PIX + n0 + px0] = s8;
        }
    }
}

// ---------------------------------------------------------------------------
// K2: MFMA flash attention, V-in-registers structure.
// grid 512: bid&7 = pb*2+mh (XCD-local K/V slice), bid>>3 = nt (64-row tile).
// QK phase: wave w computes P rows [16w,16w+16) -> block-shared p_lds.
// PV phase: wave w computes O^T c-rows [32w,32w+32) x all 64 n; V A-frags
// prefetched global->reg (double-buffered, one chunk ahead) - NO V LDS.
// K staged reg->LDS by wave 3. 2-way m-split partials, no atomics:
// mh=0 -> f32 in out1/out2 c<128 (merged in-place); mh=1 -> f32 tiled
// [pb][nt][c][64] in feat region. LDS 12.3KB -> 4 blocks/CU.
// ---------------------------------------------------------------------------
__global__ __launch_bounds__(256, 4) void attn_kernel(
    const short* __restrict__ qg, const short* __restrict__ kg,
    const short* __restrict__ vg,
    float* __restrict__ out1, float* __restrict__ out2,
    float* __restrict__ featf, float* __restrict__ lpart)
{
    __shared__ short k_lds[64 * 24];   // [m][d], pitch 24 shorts (48B)
    __shared__ short p_lds[64 * 72];   // [n][m], pitch 72 shorts (144B), shared

    const int tid = threadIdx.x;
    const int lane = tid & 63;
    const int w = tid >> 6;
    const int gk = lane >> 4;
    const int l15 = lane & 15;

    const int B_ = blockIdx.x;
    const int pm = B_ & 7;
    const int pb = pm >> 1, mh = pm & 1;
    const int nt = B_ >> 3;
    const int n0 = nt * 64;
    const int br = pb >> 1, b = pb & 1;

    const short* qp = qg + (size_t)pb * N_PIX * 16;
    const short* kp = kg + (size_t)((br ^ 1) * 2 + b) * N_PIX * 16 + (size_t)(mh * 2048) * 16;
    const short* vp = vg + (size_t)pb * DV * N_PIX + mh * 2048;

    // constant Q A-fragment (lanes>=32 zero-pad d 16..31)
    bf16x8 aq = {};
    if (lane < 32)
        aq = *(const bf16x8*)&qp[(size_t)(n0 + w * 16 + l15) * 16 + gk * 8];

    f32x4 acc[2][4];
    #pragma unroll
    for (int cc = 0; cc < 2; ++cc)
        #pragma unroll
        for (int nb = 0; nb < 4; ++nb) acc[cc][nb] = (f32x4){0.f, 0.f, 0.f, 0.f};
    float lsum[4] = {0.f, 0.f, 0.f, 0.f};

    // V A-frag base: wave w owns c-rows [32w, 32w+32)
    const short* vbase = vp + (size_t)(w * 32 + l15) * N_PIX + gk * 8;
    const int krow = tid - 192;

    int4 vbuf0[4], vbuf1[4];
    int4 kr0 = {}, kr1 = {};

    {   // prologue: chunk 0 V->regs, K->LDS
        #pragma unroll
        for (int cc = 0; cc < 2; ++cc)
            #pragma unroll
            for (int m2 = 0; m2 < 2; ++m2)
                vbuf0[cc * 2 + m2] = *(const int4*)&vbase[(size_t)cc * 16 * N_PIX + m2 * 32];
        if (tid >= 192) {
            kr0 = *(const int4*)&kp[(size_t)krow * 16];
            kr1 = *(const int4*)&kp[(size_t)krow * 16 + 8];
            *(int4*)&k_lds[krow * 24] = kr0;
            *(int4*)&k_lds[krow * 24 + 8] = kr1;
        }
        __syncthreads();
    }

    for (int t0 = 0; t0 < 32; t0 += 2) {
        #pragma unroll
        for (int half = 0; half < 2; ++half) {
            const int t = t0 + half;
            int4* vcur = half ? vbuf1 : vbuf0;
            int4* vnxt = half ? vbuf0 : vbuf1;
            if (t + 1 < 32) {   // prefetch chunk t+1 (consumed next PV phase)
                #pragma unroll
                for (int cc = 0; cc < 2; ++cc)
                    #pragma unroll
                    for (int m2 = 0; m2 < 2; ++m2)
                        vnxt[cc * 2 + m2] = *(const int4*)
                            &vbase[(size_t)cc * 16 * N_PIX + (t + 1) * 64 + m2 * 32];
                if (tid >= 192) {
                    kr0 = *(const int4*)&kp[(size_t)((t + 1) * 64 + krow) * 16];
                    kr1 = *(const int4*)&kp[(size_t)((t + 1) * 64 + krow) * 16 + 8];
                }
            }
            // QK^T -> exp -> P (bf16 trunc) into shared p_lds (own n-rows)
            #pragma unroll
            for (int h = 0; h < 4; ++h) {
                bf16x8 bk_ = {};
                if (lane < 32)
                    bk_ = *(const bf16x8*)&k_lds[(h * 16 + l15) * 24 + gk * 8];
                f32x4 s = __builtin_amdgcn_mfma_f32_16x16x32_bf16(
                    aq, bk_, (f32x4){0.f, 0.f, 0.f, 0.f}, 0, 0, 0);
                #pragma unroll
                for (int rr = 0; rr < 4; ++rr) {
                    float e = __expf(s[rr] * 0.25f);
                    lsum[rr] += e;
                    unsigned u = __builtin_bit_cast(unsigned, e);
                    p_lds[(w * 16 + gk * 4 + rr) * 72 + h * 16 + l15] = (short)(u >> 16);
                }
            }
            __syncthreads();   // P visible to all waves; k_lds reads done
            if (t + 1 < 32 && tid >= 192) {   // commit K(t+1); no reader until next barrier
                *(int4*)&k_lds[krow * 24] = kr0;
                *(int4*)&k_lds[krow * 24 + 8] = kr1;
            }
            // PV: O^T[c 32w..][all 64 n] += V(regs) * P^T(LDS)
            __builtin_amdgcn_s_setprio(1);
            #pragma unroll
            for (int m2 = 0; m2 < 2; ++m2) {
                #pragma unroll
                for (int nb = 0; nb < 4; ++nb) {
                    bf16x8 bp = *(const bf16x8*)&p_lds[(nb * 16 + l15) * 72 + m2 * 32 + gk * 8];
                    #pragma unroll
                    for (int cc = 0; cc < 2; ++cc) {
                        bf16x8 av = __builtin_bit_cast(bf16x8, vcur[cc * 2 + m2]);
                        acc[cc][nb] = __builtin_amdgcn_mfma_f32_16x16x32_bf16(
                            av, bp, acc[cc][nb], 0, 0, 0);
                    }
                }
            }
            __builtin_amdgcn_s_setprio(0);
            __syncthreads();   // p_lds reads done before next QK overwrite
        }
    }

    // l: reduce across the 16 m-lanes in each gk group
    #pragma unroll
    for (int rr = 0; rr < 4; ++rr) {
        float v = lsum[rr];
        v += __shfl_xor(v, 1); v += __shfl_xor(v, 2);
        v += __shfl_xor(v, 4); v += __shfl_xor(v, 8);
        lsum[rr] = v;
    }
    if (l15 == 0) {
        #pragma unroll
        for (int rr = 0; rr < 4; ++rr)
            lpart[(size_t)(pb * 2 + mh) * N_PIX + n0 + w * 16 + gk * 4 + rr] = lsum[rr];
    }

    if (mh == 0) {   // f32 partial at final location (c<128 of out1/out2)
        float* Od = (br ? out2 : out1) + (size_t)b * CCH * N_PIX;
        #pragma unroll
        for (int cc = 0; cc < 2; ++cc)
            #pragma unroll
            for (int nb = 0; nb < 4; ++nb)
                #pragma unroll
                for (int rr = 0; rr < 4; ++rr) {
                    int c = w * 32 + cc * 16 + gk * 4 + rr;
                    Od[(size_t)c * N_PIX + n0 + nb * 16 + l15] = acc[cc][nb][rr];
                }
    } else {         // f32 tiled partial [pb][nt][c][64] in feat region
        float* Ps = featf + (size_t)(pb * 64 + nt) * (128 * 64);
        #pragma unroll
        for (int cc = 0; cc < 2; ++cc)
            #pragma unroll
            for (int nb = 0; nb < 4; ++nb)
                #pragma unroll
                for (int rr = 0; rr < 4; ++rr) {
                    int c = w * 32 + cc * 16 + gk * 4 + rr;
                    Ps[c * 64 + nb * 16 + l15] = acc[cc][nb][rr];
                }
    }
}

// ---------------------------------------------------------------------------
// K2b: merge 2 partials + epilogue + prep_s fused.
// out1/out2: c<128 -> gamma*(P0+P1)/(l0+l1) + x_self;
//            c>=128 -> gamma*x_self[c-128] + x_self.
// Also writes s_t[b][px][c] = bf16(out1+out2). grid (128,2), block 256.
// ---------------------------------------------------------------------------
__global__ __launch_bounds__(256) void merge_kernel(
    const float* __restrict__ x1, const float* __restrict__ x2,
    const float* __restrict__ featf, const float* __restrict__ lpart,
    const float* __restrict__ gamma_p,
    float* __restrict__ out1, float* __restrict__ out2,
    short* __restrict__ s_t)
{
    __shared__ short st[32 * 264];
    __shared__ float rls[2][32];
    const int tid = threadIdx.x;
    const int px0 = blockIdx.x * 32;
    const int b = blockIdx.y;
    const int nt = blockIdx.x >> 1;
    const int q32 = (blockIdx.x & 1) * 32;
    const float* xa_ = x1 + (size_t)b * CCH * N_PIX;
    const float* xb_ = x2 + (size_t)b * CCH * N_PIX;
    float* o1 = out1 + (size_t)b * CCH * N_PIX;   // holds pb=b   mh=0 partial (c<128)
    float* o2 = out2 + (size_t)b * CCH * N_PIX;   // holds pb=2+b mh=0 partial
    const float* T1 = featf + (size_t)(b * 64 + nt) * (128 * 64);        // pb=b   mh=1
    const float* T2 = featf + (size_t)((2 + b) * 64 + nt) * (128 * 64);  // pb=2+b mh=1

    if (tid < 64) {
        int h = tid >> 5, j = tid & 31;
        int pbh = h ? (2 + b) : b;
        float l = lpart[(size_t)(pbh * 2 + 0) * N_PIX + px0 + j]
                + lpart[(size_t)(pbh * 2 + 1) * N_PIX + px0 + j];
        rls[h][j] = 1.0f / l;
    }
    __syncthreads();
    const float gmm = gamma_p[0];

    for (int idx = tid; idx < 2048; idx += 256) {   // 256 c x 8 px4
        int c = idx >> 3, p4 = idx & 7;
        size_t off = (size_t)c * N_PIX + px0 + p4 * 4;
        float4 va = *(const float4*)&xa_[off];
        float4 vb2 = *(const float4*)&xb_[off];
        float4 r1, r2;
        if (c < 128) {
            float4 pa = *(const float4*)&o1[off];
            float4 pc = *(const float4*)&o2[off];
            float4 a1 = *(const float4*)&T1[c * 64 + q32 + p4 * 4];
            float4 c1 = *(const float4*)&T2[c * 64 + q32 + p4 * 4];
            r1.x = gmm * (pa.x + a1.x) * rls[0][p4 * 4 + 0] + va.x;
            r1.y = gmm * (pa.y + a1.y) * rls[0][p4 * 4 + 1] + va.y;
            r1.z = gmm * (pa.z + a1.z) * rls[0][p4 * 4 + 2] + va.z;
            r1.w = gmm * (pa.w + a1.w) * rls[0][p4 * 4 + 3] + va.w;
            r2.x = gmm * (pc.x + c1.x) * rls[1][p4 * 4 + 0] + vb2.x;
            r2.y = gmm * (pc.y + c1.y) * rls[1][p4 * 4 + 1] + vb2.y;
            r2.z = gmm * (pc.z + c1.z) * rls[1][p4 * 4 + 2] + vb2.z;
            r2.w = gmm * (pc.w + c1.w) * rls[1][p4 * 4 + 3] + vb2.w;
        } else {
            size_t offl = (size_t)(c - 128) * N_PIX + px0 + p4 * 4;
            float4 val = *(const float4*)&xa_[offl];
            float4 vbl = *(const float4*)&xb_[offl];
            r1.x = gmm * val.x + va.x; r1.y = gmm * val.y + va.y;
            r1.z = gmm * val.z + va.z; r1.w = gmm * val.w + va.w;
            r2.x = gmm * vbl.x + vb2.x; r2.y = gmm * vbl.y + vb2.y;
            r2.z = gmm * vbl.z + vb2.z; r2.w = gmm * vbl.w + vb2.w;
        }
        *(float4*)&o1[off] = r1;
        *(float4*)&o2[off] = r2;
        st[(p4 * 4 + 0) * 264 + c] = f2bf(r1.x + r2.x);
        st[(p4 * 4 + 1) * 264 + c] = f2bf(r1.y + r2.y);
        st[(p4 * 4 + 2) * 264 + c] = f2bf(r1.z + r2.z);
        st[(p4 * 4 + 3) * 264 + c] = f2bf(r1.w + r2.w);
    }
    __syncthreads();
    for (int idx = tid; idx < 1024; idx += 256) {   // 32 px x 32 seg
        int px = idx >> 5, seg = idx & 31;
        int4 v = *(const int4*)&st[px * 264 + seg * 8];
        *(int4*)&s_t[((size_t)b * N_PIX + px0 + px) * CCH + seg * 8] = v;
    }
}

// ---------------------------------------------------------------------------
// K3b: prep_w — Wcat fp32 [oc][ic][3][3] -> bf16 A-fragment order
// ---------------------------------------------------------------------------
__global__ __launch_bounds__(256) void prep_w(
    const float* __restrict__ Wcat, short* __restrict__ wfmt)
{
    int idx = blockIdx.x * 256 + threadIdx.x;
    int lane = idx & 63;
    int ocg = (idx >> 6) & 15;
    int chunk = (idx >> 10) & 7;
    int tap = idx >> 13;
    int oc = ocg * 16 + (lane & 15);
    int ic0 = chunk * 32 + (lane >> 4) * 8;
    short8 v;
    #pragma unroll
    for (int j = 0; j < 8; ++j)
        v[j] = f2bf(Wcat[((size_t)oc * CCH + ic0 + j) * 9 + tap]);
    *(short8*)&wfmt[(size_t)idx * 8] = v;
}

// ---------------------------------------------------------------------------
// K3c: conv as implicit GEMM on MFMA (unchanged)
// ---------------------------------------------------------------------------
__global__ __launch_bounds__(256) void conv_mfma(
    const short* __restrict__ s_t, const short* __restrict__ wfmt,
    const float* __restrict__ bn_gamma, const float* __restrict__ bn_beta,
    float* __restrict__ feat)
{
    __shared__ short s_lds[264 * 40];
    const int tid = threadIdx.x;
    const int lane = tid & 63;
    const int wv = tid >> 6;
    const int g = lane >> 4, l15 = lane & 15;

    const int bx = blockIdx.x;
    const int oc_t = bx & 3;
    const int pt = bx >> 2;
    const int b = pt >> 5;
    const int h0 = (pt & 31) * 2;

    f32x4 acc[2][4] = {};

    const short* sbase = s_t + (size_t)b * N_PIX * CCH;
    const short* wf = wfmt + ((size_t)(oc_t * 4) * 64 + lane) * 8;

    for (int ci = 0; ci < 8; ++ci) {
        const int ic0 = ci * 32;
        __syncthreads();
        for (int idx = tid; idx < 1056; idx += 256) {
            int seg = idx & 3, pos = idx >> 2;
            int row = pos / 66, wi = pos - row * 66;
            int hr = h0 - 1 + row, w = wi - 1;
            int4 val = {0, 0, 0, 0};
            if (hr >= 0 && hr < 64 && (unsigned)w < 64u)
                val = *(const int4*)&sbase[((size_t)(hr * 64 + w)) * CCH + ic0 + seg * 8];
            *(int4*)&s_lds[pos * 40 + seg * 8] = val;
        }
        __syncthreads();

        const short* wfc = wf + (size_t)ci * 8192;
        bf16x8 a0[4], a1[4];
        #pragma unroll
        for (int j = 0; j < 4; ++j) a0[j] = *(const bf16x8*)&wfc[j * 512];

        for (int tap = 0; tap < 9; ++tap) {
            bf16x8* ac = (tap & 1) ? a1 : a0;
            bf16x8* an = (tap & 1) ? a0 : a1;
            if (tap < 8) {
                const short* wfn = wfc + (size_t)(tap + 1) * 65536;
                #pragma unroll
                for (int j = 0; j < 4; ++j) an[j] = *(const bf16x8*)&wfn[j * 512];
            }
            int ky = (tap >= 6) ? 2 : (tap >= 3 ? 1 : 0);
            int kx = tap - ky * 3;
            #pragma unroll
            for (int f = 0; f < 2; ++f) {
                int fr = wv * 2 + f;
                int rl = fr >> 2, wc0 = (fr & 3) * 16;
                bf16x8 bb = *(const bf16x8*)
                    &s_lds[((rl + ky) * 66 + wc0 + l15 + kx) * 40 + g * 8];
                #pragma unroll
                for (int j = 0; j < 4; ++j)
                    acc[f][j] = __builtin_amdgcn_mfma_f32_16x16x32_bf16(
                        ac[j], bb, acc[f][j], 0, 0, 0);
            }
        }
    }

    const float inv = rsqrtf(1.0f + 1e-5f);
    #pragma unroll
    for (int f = 0; f < 2; ++f) {
        int fr = wv * 2 + f;
        int rl = fr >> 2, wc0 = (fr & 3) * 16;
        int h = h0 + rl, wcol = wc0 + l15;
        #pragma unroll
        for (int j = 0; j < 4; ++j) {
            #pragma unroll
            for (int r = 0; r < 4; ++r) {
                int oc = oc_t * 64 + j * 16 + g * 4 + r;
                float y = acc[f][j][r] * (bn_gamma[oc] * inv) + bn_beta[oc];
                feat[((size_t)b * CCH + oc) * N_PIX + h * 64 + wcol] = fmaxf(y, 0.f);
            }
        }
    }
}

// ---------------------------------------------------------------------------
extern "C" void kernel_launch(void* const* d_in, const int* in_sizes, int n_in,
                              void* d_out, int out_size, void* d_ws, size_t ws_size,
                              hipStream_t stream) {
    const float* x1    = (const float*)d_in[0];
    const float* x2    = (const float*)d_in[1];
    const float* Wq    = (const float*)d_in[2];
    const float* bq    = (const float*)d_in[3];
    const float* Wk    = (const float*)d_in[4];
    const float* bk    = (const float*)d_in[5];
    const float* Wv    = (const float*)d_in[6];
    const float* bv    = (const float*)d_in[7];
    const float* gamma = (const float*)d_in[8];
    const float* Wcat  = (const float*)d_in[9];
    const float* bng   = (const float*)d_in[10];
    const float* bnb   = (const float*)d_in[11];

    float* out  = (float*)d_out;
    float* feat = out;                    // hosts 4 f32 tiled partial slots pre-conv
    float* out1 = out + 2097152;
    float* out2 = out + 4194304;

    short* ws   = (short*)d_ws;
    short* qb   = ws;                     // 262144 shorts
    short* kb   = ws + 262144;            // 262144
    short* vb   = ws + 524288;            // 2097152
    short* s_t  = ws + 2621440;           // 2097152
    short* wfmt = ws + 4718592;           // 589824
    float* lp   = (float*)(ws + 5308416); // 8*4096 f32 l-partials

    prep_w<<<288, 256, 0, stream>>>(Wcat, wfmt);
    qkv_kernel<<<dim3(64, 4), 256, 0, stream>>>(x1, x2, Wq, bq, Wk, bk, Wv, bv, qb, kb, vb);
    attn_kernel<<<512, 256, 0, stream>>>(qb, kb, vb, out1, out2, feat, lp);
    merge_kernel<<<dim3(128, 2), 256, 0, stream>>>(x1, x2, feat, lp, gamma, out1, out2, s_t);
    conv_mfma<<<256, 256, 0, stream>>>(s_t, wfmt, bng, bnb, feat);
}

// Round 10
// 109.115 us; speedup vs baseline: 1.8267x; 1.2333x over previous
//
#include <hip/hip_runtime.h>

#define N_PIX 4096
#define CCH 256
#define DV 128

typedef __attribute__((ext_vector_type(8))) short bf16x8;
typedef __attribute__((ext_vector_type(4))) float f32x4;
typedef __attribute__((ext_vector_type(8))) short short8;

__device__ __forceinline__ short f2bf(float f) {
    unsigned u = __builtin_bit_cast(unsigned, f);
    u += 0x7fffu + ((u >> 16) & 1u);
    return (short)(u >> 16);
}

// ---------------------------------------------------------------------------
// K1: fused 1x1 convs as ONE bf16 MFMA GEMM.
// out[r][px] = sum_c W[r][c] x[c][px], M=160 (q16|k16|v128), K=256 = 4 chunks
// of 64 c (2 MFMAs each). A = x^T (staged f32->bf16 transposed in LDS per
// chunk), B = wqkv bf16 (global, L2-resident). D: col=r (lane&15),
// row=px ((lane>>4)*4+reg) -> V stores coalesced short4; q/k small scatter.
// grid (64,4): x = 64-px tile, y = ib. block 512 (8 waves, 2/SIMD).
// ---------------------------------------------------------------------------
__global__ __launch_bounds__(512) void qkv_kernel(
    const float* __restrict__ x1, const float* __restrict__ x2,
    const short* __restrict__ wqkv,
    const float* __restrict__ bq, const float* __restrict__ bk,
    const float* __restrict__ bv,
    short* __restrict__ qb, short* __restrict__ kb, short* __restrict__ vb)
{
    __shared__ short xT[64][68];   // [px][c-chunk], pitch 68 shorts

    const int tid = threadIdx.x;
    const int lane = tid & 63;
    const int w = tid >> 6;
    const int g = lane >> 4, l15 = lane & 15;
    const int n0 = blockIdx.x * 64;
    const int ib = blockIdx.y;
    const int i = ib >> 1, b = ib & 1;
    const float* x = (i == 0 ? x1 : x2) + (size_t)b * CCH * N_PIX;

    // staging map: px2 = pixel pair, c4 = 4-c group (c4 0..15)
    const int px2 = tid & 31, c4 = tid >> 5;

    // compute map: wave w -> px [(w&3)*16, +16), r base (w>>2)*80
    const int rhalf = (w >> 2) * 80;

    f32x4 acc[5];
    #pragma unroll
    for (int jl = 0; jl < 5; ++jl) {
        int rbase = rhalf + jl * 16;
        float bias;
        if (rbase == 0)       bias = bq[l15];
        else if (rbase == 16) bias = bk[l15];
        else                  bias = bv[rbase - 32 + l15];
        acc[jl] = (f32x4){bias, bias, bias, bias};
    }

    float2 xr[4];
    {   // prefetch chunk 0 (channels 0..63)
        #pragma unroll
        for (int jj = 0; jj < 4; ++jj)
            xr[jj] = *(const float2*)&x[(size_t)(c4 * 4 + jj) * N_PIX + n0 + px2 * 2];
    }

    for (int ci = 0; ci < 4; ++ci) {   // 4 chunks x 64 c = K 256
        __syncthreads();   // previous chunk's A-reads done
        {   // transpose 4c x 2px micro-tile -> 2 short4 LDS writes
            short4 w0, w1;
            w0.x = f2bf(xr[0].x); w0.y = f2bf(xr[1].x); w0.z = f2bf(xr[2].x); w0.w = f2bf(xr[3].x);
            w1.x = f2bf(xr[0].y); w1.y = f2bf(xr[1].y); w1.z = f2bf(xr[2].y); w1.w = f2bf(xr[3].y);
            *(short4*)&xT[px2 * 2 + 0][c4 * 4] = w0;
            *(short4*)&xT[px2 * 2 + 1][c4 * 4] = w1;
        }
        __syncthreads();
        if (ci < 3) {   // prefetch next chunk; hides under compute
            #pragma unroll
            for (int jj = 0; jj < 4; ++jj)
                xr[jj] = *(const float2*)
                    &x[(size_t)((ci + 1) * 64 + c4 * 4 + jj) * N_PIX + n0 + px2 * 2];
        }
        // A-frags from LDS (this wave's 16 px), B-frags from L2-hot wqkv
        bf16x8 a0 = *(const bf16x8*)&xT[(w & 3) * 16 + l15][g * 8];
        bf16x8 a1 = *(const bf16x8*)&xT[(w & 3) * 16 + l15][32 + g * 8];
        #pragma unroll
        for (int jl = 0; jl < 5; ++jl) {
            int rbase = rhalf + jl * 16;
            const short* wrow = wqkv + (size_t)(rbase + l15) * CCH + ci * 64;
            bf16x8 b0 = *(const bf16x8*)&wrow[g * 8];
            bf16x8 b1 = *(const bf16x8*)&wrow[32 + g * 8];
            acc[jl] = __builtin_amdgcn_mfma_f32_16x16x32_bf16(a0, b0, acc[jl], 0, 0, 0);
            acc[jl] = __builtin_amdgcn_mfma_f32_16x16x32_bf16(a1, b1, acc[jl], 0, 0, 0);
        }
    }

    const int px_base = n0 + (w & 3) * 16 + g * 4;
    #pragma unroll
    for (int jl = 0; jl < 5; ++jl) {
        int rbase = rhalf + jl * 16;
        if (rbase == 0) {
            #pragma unroll
            for (int rr = 0; rr < 4; ++rr)
                qb[((size_t)ib * N_PIX + px_base + rr) * 16 + l15] = f2bf(acc[jl][rr]);
        } else if (rbase == 16) {
            #pragma unroll
            for (int rr = 0; rr < 4; ++rr)
                kb[((size_t)ib * N_PIX + px_base + rr) * 16 + l15] = f2bf(acc[jl][rr]);
        } else {
            int c = rbase - 32 + l15;
            short4 s;
            s.x = f2bf(acc[jl][0]); s.y = f2bf(acc[jl][1]);
            s.z = f2bf(acc[jl][2]); s.w = f2bf(acc[jl][3]);
            *(short4*)&vb[((size_t)ib * DV + c) * N_PIX + px_base] = s;
        }
    }
}

// ---------------------------------------------------------------------------
// K2: MFMA flash attention, V-in-registers structure (unchanged from r8).
// ---------------------------------------------------------------------------
__global__ __launch_bounds__(256, 4) void attn_kernel(
    const short* __restrict__ qg, const short* __restrict__ kg,
    const short* __restrict__ vg,
    float* __restrict__ out1, float* __restrict__ out2,
    float* __restrict__ featf, float* __restrict__ lpart)
{
    __shared__ short k_lds[64 * 24];   // [m][d], pitch 24 shorts (48B)
    __shared__ short p_lds[64 * 72];   // [n][m], pitch 72 shorts (144B), shared

    const int tid = threadIdx.x;
    const int lane = tid & 63;
    const int w = tid >> 6;
    const int gk = lane >> 4;
    const int l15 = lane & 15;

    const int B_ = blockIdx.x;
    const int pm = B_ & 7;
    const int pb = pm >> 1, mh = pm & 1;
    const int nt = B_ >> 3;
    const int n0 = nt * 64;
    const int br = pb >> 1, b = pb & 1;

    const short* qp = qg + (size_t)pb * N_PIX * 16;
    const short* kp = kg + (size_t)((br ^ 1) * 2 + b) * N_PIX * 16 + (size_t)(mh * 2048) * 16;
    const short* vp = vg + (size_t)pb * DV * N_PIX + mh * 2048;

    bf16x8 aq = {};
    if (lane < 32)
        aq = *(const bf16x8*)&qp[(size_t)(n0 + w * 16 + l15) * 16 + gk * 8];

    f32x4 acc[2][4];
    #pragma unroll
    for (int cc = 0; cc < 2; ++cc)
        #pragma unroll
        for (int nb = 0; nb < 4; ++nb) acc[cc][nb] = (f32x4){0.f, 0.f, 0.f, 0.f};
    float lsum[4] = {0.f, 0.f, 0.f, 0.f};

    const short* vbase = vp + (size_t)(w * 32 + l15) * N_PIX + gk * 8;
    const int krow = tid - 192;

    int4 vbuf0[4], vbuf1[4];
    int4 kr0 = {}, kr1 = {};

    {
        #pragma unroll
        for (int cc = 0; cc < 2; ++cc)
            #pragma unroll
            for (int m2 = 0; m2 < 2; ++m2)
                vbuf0[cc * 2 + m2] = *(const int4*)&vbase[(size_t)cc * 16 * N_PIX + m2 * 32];
        if (tid >= 192) {
            kr0 = *(const int4*)&kp[(size_t)krow * 16];
            kr1 = *(const int4*)&kp[(size_t)krow * 16 + 8];
            *(int4*)&k_lds[krow * 24] = kr0;
            *(int4*)&k_lds[krow * 24 + 8] = kr1;
        }
        __syncthreads();
    }

    for (int t0 = 0; t0 < 32; t0 += 2) {
        #pragma unroll
        for (int half = 0; half < 2; ++half) {
            const int t = t0 + half;
            int4* vcur = half ? vbuf1 : vbuf0;
            int4* vnxt = half ? vbuf0 : vbuf1;
            if (t + 1 < 32) {
                #pragma unroll
                for (int cc = 0; cc < 2; ++cc)
                    #pragma unroll
                    for (int m2 = 0; m2 < 2; ++m2)
                        vnxt[cc * 2 + m2] = *(const int4*)
                            &vbase[(size_t)cc * 16 * N_PIX + (t + 1) * 64 + m2 * 32];
                if (tid >= 192) {
                    kr0 = *(const int4*)&kp[(size_t)((t + 1) * 64 + krow) * 16];
                    kr1 = *(const int4*)&kp[(size_t)((t + 1) * 64 + krow) * 16 + 8];
                }
            }
            #pragma unroll
            for (int h = 0; h < 4; ++h) {
                bf16x8 bk_ = {};
                if (lane < 32)
                    bk_ = *(const bf16x8*)&k_lds[(h * 16 + l15) * 24 + gk * 8];
                f32x4 s = __builtin_amdgcn_mfma_f32_16x16x32_bf16(
                    aq, bk_, (f32x4){0.f, 0.f, 0.f, 0.f}, 0, 0, 0);
                #pragma unroll
                for (int rr = 0; rr < 4; ++rr) {
                    float e = __expf(s[rr] * 0.25f);
                    lsum[rr] += e;
                    unsigned u = __builtin_bit_cast(unsigned, e);
                    p_lds[(w * 16 + gk * 4 + rr) * 72 + h * 16 + l15] = (short)(u >> 16);
                }
            }
            __syncthreads();
            if (t + 1 < 32 && tid >= 192) {
                *(int4*)&k_lds[krow * 24] = kr0;
                *(int4*)&k_lds[krow * 24 + 8] = kr1;
            }
            __builtin_amdgcn_s_setprio(1);
            #pragma unroll
            for (int m2 = 0; m2 < 2; ++m2) {
                #pragma unroll
                for (int nb = 0; nb < 4; ++nb) {
                    bf16x8 bp = *(const bf16x8*)&p_lds[(nb * 16 + l15) * 72 + m2 * 32 + gk * 8];
                    #pragma unroll
                    for (int cc = 0; cc < 2; ++cc) {
                        bf16x8 av = __builtin_bit_cast(bf16x8, vcur[cc * 2 + m2]);
                        acc[cc][nb] = __builtin_amdgcn_mfma_f32_16x16x32_bf16(
                            av, bp, acc[cc][nb], 0, 0, 0);
                    }
                }
            }
            __builtin_amdgcn_s_setprio(0);
            __syncthreads();
        }
    }

    #pragma unroll
    for (int rr = 0; rr < 4; ++rr) {
        float v = lsum[rr];
        v += __shfl_xor(v, 1); v += __shfl_xor(v, 2);
        v += __shfl_xor(v, 4); v += __shfl_xor(v, 8);
        lsum[rr] = v;
    }
    if (l15 == 0) {
        #pragma unroll
        for (int rr = 0; rr < 4; ++rr)
            lpart[(size_t)(pb * 2 + mh) * N_PIX + n0 + w * 16 + gk * 4 + rr] = lsum[rr];
    }

    if (mh == 0) {
        float* Od = (br ? out2 : out1) + (size_t)b * CCH * N_PIX;
        #pragma unroll
        for (int cc = 0; cc < 2; ++cc)
            #pragma unroll
            for (int nb = 0; nb < 4; ++nb)
                #pragma unroll
                for (int rr = 0; rr < 4; ++rr) {
                    int c = w * 32 + cc * 16 + gk * 4 + rr;
                    Od[(size_t)c * N_PIX + n0 + nb * 16 + l15] = acc[cc][nb][rr];
                }
    } else {
        float* Ps = featf + (size_t)(pb * 64 + nt) * (128 * 64);
        #pragma unroll
        for (int cc = 0; cc < 2; ++cc)
            #pragma unroll
            for (int nb = 0; nb < 4; ++nb)
                #pragma unroll
                for (int rr = 0; rr < 4; ++rr) {
                    int c = w * 32 + cc * 16 + gk * 4 + rr;
                    Ps[c * 64 + nb * 16 + l15] = acc[cc][nb][rr];
                }
    }
}

// ---------------------------------------------------------------------------
// K2b: merge 2 partials + epilogue + prep_s fused (unchanged from r8).
// ---------------------------------------------------------------------------
__global__ __launch_bounds__(256) void merge_kernel(
    const float* __restrict__ x1, const float* __restrict__ x2,
    const float* __restrict__ featf, const float* __restrict__ lpart,
    const float* __restrict__ gamma_p,
    float* __restrict__ out1, float* __restrict__ out2,
    short* __restrict__ s_t)
{
    __shared__ short st[32 * 264];
    __shared__ float rls[2][32];
    const int tid = threadIdx.x;
    const int px0 = blockIdx.x * 32;
    const int b = blockIdx.y;
    const int nt = blockIdx.x >> 1;
    const int q32 = (blockIdx.x & 1) * 32;
    const float* xa_ = x1 + (size_t)b * CCH * N_PIX;
    const float* xb_ = x2 + (size_t)b * CCH * N_PIX;
    float* o1 = out1 + (size_t)b * CCH * N_PIX;
    float* o2 = out2 + (size_t)b * CCH * N_PIX;
    const float* T1 = featf + (size_t)(b * 64 + nt) * (128 * 64);
    const float* T2 = featf + (size_t)((2 + b) * 64 + nt) * (128 * 64);

    if (tid < 64) {
        int h = tid >> 5, j = tid & 31;
        int pbh = h ? (2 + b) : b;
        float l = lpart[(size_t)(pbh * 2 + 0) * N_PIX + px0 + j]
                + lpart[(size_t)(pbh * 2 + 1) * N_PIX + px0 + j];
        rls[h][j] = 1.0f / l;
    }
    __syncthreads();
    const float gmm = gamma_p[0];

    for (int idx = tid; idx < 2048; idx += 256) {
        int c = idx >> 3, p4 = idx & 7;
        size_t off = (size_t)c * N_PIX + px0 + p4 * 4;
        float4 va = *(const float4*)&xa_[off];
        float4 vb2 = *(const float4*)&xb_[off];
        float4 r1, r2;
        if (c < 128) {
            float4 pa = *(const float4*)&o1[off];
            float4 pc = *(const float4*)&o2[off];
            float4 a1 = *(const float4*)&T1[c * 64 + q32 + p4 * 4];
            float4 c1 = *(const float4*)&T2[c * 64 + q32 + p4 * 4];
            r1.x = gmm * (pa.x + a1.x) * rls[0][p4 * 4 + 0] + va.x;
            r1.y = gmm * (pa.y + a1.y) * rls[0][p4 * 4 + 1] + va.y;
            r1.z = gmm * (pa.z + a1.z) * rls[0][p4 * 4 + 2] + va.z;
            r1.w = gmm * (pa.w + a1.w) * rls[0][p4 * 4 + 3] + va.w;
            r2.x = gmm * (pc.x + c1.x) * rls[1][p4 * 4 + 0] + vb2.x;
            r2.y = gmm * (pc.y + c1.y) * rls[1][p4 * 4 + 1] + vb2.y;
            r2.z = gmm * (pc.z + c1.z) * rls[1][p4 * 4 + 2] + vb2.z;
            r2.w = gmm * (pc.w + c1.w) * rls[1][p4 * 4 + 3] + vb2.w;
        } else {
            size_t offl = (size_t)(c - 128) * N_PIX + px0 + p4 * 4;
            float4 val = *(const float4*)&xa_[offl];
            float4 vbl = *(const float4*)&xb_[offl];
            r1.x = gmm * val.x + va.x; r1.y = gmm * val.y + va.y;
            r1.z = gmm * val.z + va.z; r1.w = gmm * val.w + va.w;
            r2.x = gmm * vbl.x + vb2.x; r2.y = gmm * vbl.y + vb2.y;
            r2.z = gmm * vbl.z + vb2.z; r2.w = gmm * vbl.w + vb2.w;
        }
        *(float4*)&o1[off] = r1;
        *(float4*)&o2[off] = r2;
        st[(p4 * 4 + 0) * 264 + c] = f2bf(r1.x + r2.x);
        st[(p4 * 4 + 1) * 264 + c] = f2bf(r1.y + r2.y);
        st[(p4 * 4 + 2) * 264 + c] = f2bf(r1.z + r2.z);
        st[(p4 * 4 + 3) * 264 + c] = f2bf(r1.w + r2.w);
    }
    __syncthreads();
    for (int idx = tid; idx < 1024; idx += 256) {
        int px = idx >> 5, seg = idx & 31;
        int4 v = *(const int4*)&st[px * 264 + seg * 8];
        *(int4*)&s_t[((size_t)b * N_PIX + px0 + px) * CCH + seg * 8] = v;
    }
}

// ---------------------------------------------------------------------------
// K3b: prep_w — blocks <288: Wcat -> bf16 A-fragment order.
//      blocks >=288 (40): pack Wq|Wk|Wv -> wqkv bf16 [160][256].
// ---------------------------------------------------------------------------
__global__ __launch_bounds__(256) void prep_w(
    const float* __restrict__ Wcat,
    const float* __restrict__ Wq, const float* __restrict__ Wk,
    const float* __restrict__ Wv,
    short* __restrict__ wfmt, short* __restrict__ wqkv)
{
    if (blockIdx.x < 288) {
        int idx = blockIdx.x * 256 + threadIdx.x;
        int lane = idx & 63;
        int ocg = (idx >> 6) & 15;
        int chunk = (idx >> 10) & 7;
        int tap = idx >> 13;
        int oc = ocg * 16 + (lane & 15);
        int ic0 = chunk * 32 + (lane >> 4) * 8;
        short8 v;
        #pragma unroll
        for (int j = 0; j < 8; ++j)
            v[j] = f2bf(Wcat[((size_t)oc * CCH + ic0 + j) * 9 + tap]);
        *(short8*)&wfmt[(size_t)idx * 8] = v;
    } else {
        int idx = (blockIdx.x - 288) * 1024 + threadIdx.x * 4;   // 0..40959
        int r = idx >> 8, c = idx & 255;
        const float* src;
        if (r < 16)      src = Wq + (size_t)r * CCH + c;
        else if (r < 32) src = Wk + (size_t)(r - 16) * CCH + c;
        else             src = Wv + (size_t)(r - 32) * CCH + c;
        float4 f = *(const float4*)src;
        short4 s;
        s.x = f2bf(f.x); s.y = f2bf(f.y); s.z = f2bf(f.z); s.w = f2bf(f.w);
        *(short4*)&wqkv[idx] = s;
    }
}

// ---------------------------------------------------------------------------
// K3c: conv as implicit GEMM on MFMA (unchanged)
// ---------------------------------------------------------------------------
__global__ __launch_bounds__(256) void conv_mfma(
    const short* __restrict__ s_t, const short* __restrict__ wfmt,
    const float* __restrict__ bn_gamma, const float* __restrict__ bn_beta,
    float* __restrict__ feat)
{
    __shared__ short s_lds[264 * 40];
    const int tid = threadIdx.x;
    const int lane = tid & 63;
    const int wv = tid >> 6;
    const int g = lane >> 4, l15 = lane & 15;

    const int bx = blockIdx.x;
    const int oc_t = bx & 3;
    const int pt = bx >> 2;
    const int b = pt >> 5;
    const int h0 = (pt & 31) * 2;

    f32x4 acc[2][4] = {};

    const short* sbase = s_t + (size_t)b * N_PIX * CCH;
    const short* wf = wfmt + ((size_t)(oc_t * 4) * 64 + lane) * 8;

    for (int ci = 0; ci < 8; ++ci) {
        const int ic0 = ci * 32;
        __syncthreads();
        for (int idx = tid; idx < 1056; idx += 256) {
            int seg = idx & 3, pos = idx >> 2;
            int row = pos / 66, wi = pos - row * 66;
            int hr = h0 - 1 + row, w = wi - 1;
            int4 val = {0, 0, 0, 0};
            if (hr >= 0 && hr < 64 && (unsigned)w < 64u)
                val = *(const int4*)&sbase[((size_t)(hr * 64 + w)) * CCH + ic0 + seg * 8];
            *(int4*)&s_lds[pos * 40 + seg * 8] = val;
        }
        __syncthreads();

        const short* wfc = wf + (size_t)ci * 8192;
        bf16x8 a0[4], a1[4];
        #pragma unroll
        for (int j = 0; j < 4; ++j) a0[j] = *(const bf16x8*)&wfc[j * 512];

        for (int tap = 0; tap < 9; ++tap) {
            bf16x8* ac = (tap & 1) ? a1 : a0;
            bf16x8* an = (tap & 1) ? a0 : a1;
            if (tap < 8) {
                const short* wfn = wfc + (size_t)(tap + 1) * 65536;
                #pragma unroll
                for (int j = 0; j < 4; ++j) an[j] = *(const bf16x8*)&wfn[j * 512];
            }
            int ky = (tap >= 6) ? 2 : (tap >= 3 ? 1 : 0);
            int kx = tap - ky * 3;
            #pragma unroll
            for (int f = 0; f < 2; ++f) {
                int fr = wv * 2 + f;
                int rl = fr >> 2, wc0 = (fr & 3) * 16;
                bf16x8 bb = *(const bf16x8*)
                    &s_lds[((rl + ky) * 66 + wc0 + l15 + kx) * 40 + g * 8];
                #pragma unroll
                for (int j = 0; j < 4; ++j)
                    acc[f][j] = __builtin_amdgcn_mfma_f32_16x16x32_bf16(
                        ac[j], bb, acc[f][j], 0, 0, 0);
            }
        }
    }

    const float inv = rsqrtf(1.0f + 1e-5f);
    #pragma unroll
    for (int f = 0; f < 2; ++f) {
        int fr = wv * 2 + f;
        int rl = fr >> 2, wc0 = (fr & 3) * 16;
        int h = h0 + rl, wcol = wc0 + l15;
        #pragma unroll
        for (int j = 0; j < 4; ++j) {
            #pragma unroll
            for (int r = 0; r < 4; ++r) {
                int oc = oc_t * 64 + j * 16 + g * 4 + r;
                float y = acc[f][j][r] * (bn_gamma[oc] * inv) + bn_beta[oc];
                feat[((size_t)b * CCH + oc) * N_PIX + h * 64 + wcol] = fmaxf(y, 0.f);
            }
        }
    }
}

// ---------------------------------------------------------------------------
extern "C" void kernel_launch(void* const* d_in, const int* in_sizes, int n_in,
                              void* d_out, int out_size, void* d_ws, size_t ws_size,
                              hipStream_t stream) {
    const float* x1    = (const float*)d_in[0];
    const float* x2    = (const float*)d_in[1];
    const float* Wq    = (const float*)d_in[2];
    const float* bq    = (const float*)d_in[3];
    const float* Wk    = (const float*)d_in[4];
    const float* bk    = (const float*)d_in[5];
    const float* Wv    = (const float*)d_in[6];
    const float* bv    = (const float*)d_in[7];
    const float* gamma = (const float*)d_in[8];
    const float* Wcat  = (const float*)d_in[9];
    const float* bng   = (const float*)d_in[10];
    const float* bnb   = (const float*)d_in[11];

    float* out  = (float*)d_out;
    float* feat = out;                    // hosts 4 f32 tiled partial slots pre-conv
    float* out1 = out + 2097152;
    float* out2 = out + 4194304;

    short* ws   = (short*)d_ws;
    short* qb   = ws;                     // 262144 shorts
    short* kb   = ws + 262144;            // 262144
    short* vb   = ws + 524288;            // 2097152
    short* s_t  = ws + 2621440;           // 2097152
    short* wfmt = ws + 4718592;           // 589824
    float* lp   = (float*)(ws + 5308416); // 8*4096 f32 l-partials
    // wqkv aliases the first 40960 shorts of s_t: dead until merge_kernel
    // writes s_t, and qkv (the only reader) finishes before merge runs.
    short* wqkv = s_t;

    prep_w<<<328, 256, 0, stream>>>(Wcat, Wq, Wk, Wv, wfmt, wqkv);
    qkv_kernel<<<dim3(64, 4), 512, 0, stream>>>(x1, x2, wqkv, bq, bk, bv, qb, kb, vb);
    attn_kernel<<<512, 256, 0, stream>>>(qb, kb, vb, out1, out2, feat, lp);
    merge_kernel<<<dim3(128, 2), 256, 0, stream>>>(x1, x2, feat, lp, gamma, out1, out2, s_t);
    conv_mfma<<<256, 256, 0, stream>>>(s_t, wfmt, bng, bnb, feat);
}

// Round 11
// 106.953 us; speedup vs baseline: 1.8636x; 1.0202x over previous
//
#include <hip/hip_runtime.h>

#define N_PIX 4096
#define CCH 256
#define DV 128

typedef __attribute__((ext_vector_type(8))) short bf16x8;
typedef __attribute__((ext_vector_type(4))) float f32x4;
typedef __attribute__((ext_vector_type(8))) short short8;

__device__ __forceinline__ short f2bf(float f) {
    unsigned u = __builtin_bit_cast(unsigned, f);
    u += 0x7fffu + ((u >> 16) & 1u);
    return (short)(u >> 16);
}

__device__ __forceinline__ float4 bf4_load(const short* p) {
    short4 s = *(const short4*)p;
    float4 f;
    f.x = __builtin_bit_cast(float, (unsigned)((unsigned short)s.x) << 16);
    f.y = __builtin_bit_cast(float, (unsigned)((unsigned short)s.y) << 16);
    f.z = __builtin_bit_cast(float, (unsigned)((unsigned short)s.z) << 16);
    f.w = __builtin_bit_cast(float, (unsigned)((unsigned short)s.w) << 16);
    return f;
}

// ---------------------------------------------------------------------------
// K1: fused 1x1 convs as ONE bf16 MFMA GEMM (unchanged from r10).
// ---------------------------------------------------------------------------
__global__ __launch_bounds__(512) void qkv_kernel(
    const float* __restrict__ x1, const float* __restrict__ x2,
    const short* __restrict__ wqkv,
    const float* __restrict__ bq, const float* __restrict__ bk,
    const float* __restrict__ bv,
    short* __restrict__ qb, short* __restrict__ kb, short* __restrict__ vb)
{
    __shared__ short xT[64][68];   // [px][c-chunk], pitch 68 shorts

    const int tid = threadIdx.x;
    const int lane = tid & 63;
    const int w = tid >> 6;
    const int g = lane >> 4, l15 = lane & 15;
    const int n0 = blockIdx.x * 64;
    const int ib = blockIdx.y;
    const int i = ib >> 1, b = ib & 1;
    const float* x = (i == 0 ? x1 : x2) + (size_t)b * CCH * N_PIX;

    const int px2 = tid & 31, c4 = tid >> 5;
    const int rhalf = (w >> 2) * 80;

    f32x4 acc[5];
    #pragma unroll
    for (int jl = 0; jl < 5; ++jl) {
        int rbase = rhalf + jl * 16;
        float bias;
        if (rbase == 0)       bias = bq[l15];
        else if (rbase == 16) bias = bk[l15];
        else                  bias = bv[rbase - 32 + l15];
        acc[jl] = (f32x4){bias, bias, bias, bias};
    }

    float2 xr[4];
    {
        #pragma unroll
        for (int jj = 0; jj < 4; ++jj)
            xr[jj] = *(const float2*)&x[(size_t)(c4 * 4 + jj) * N_PIX + n0 + px2 * 2];
    }

    for (int ci = 0; ci < 4; ++ci) {   // 4 chunks x 64 c = K 256
        __syncthreads();
        {
            short4 w0, w1;
            w0.x = f2bf(xr[0].x); w0.y = f2bf(xr[1].x); w0.z = f2bf(xr[2].x); w0.w = f2bf(xr[3].x);
            w1.x = f2bf(xr[0].y); w1.y = f2bf(xr[1].y); w1.z = f2bf(xr[2].y); w1.w = f2bf(xr[3].y);
            *(short4*)&xT[px2 * 2 + 0][c4 * 4] = w0;
            *(short4*)&xT[px2 * 2 + 1][c4 * 4] = w1;
        }
        __syncthreads();
        if (ci < 3) {
            #pragma unroll
            for (int jj = 0; jj < 4; ++jj)
                xr[jj] = *(const float2*)
                    &x[(size_t)((ci + 1) * 64 + c4 * 4 + jj) * N_PIX + n0 + px2 * 2];
        }
        bf16x8 a0 = *(const bf16x8*)&xT[(w & 3) * 16 + l15][g * 8];
        bf16x8 a1 = *(const bf16x8*)&xT[(w & 3) * 16 + l15][32 + g * 8];
        #pragma unroll
        for (int jl = 0; jl < 5; ++jl) {
            int rbase = rhalf + jl * 16;
            const short* wrow = wqkv + (size_t)(rbase + l15) * CCH + ci * 64;
            bf16x8 b0 = *(const bf16x8*)&wrow[g * 8];
            bf16x8 b1 = *(const bf16x8*)&wrow[32 + g * 8];
            acc[jl] = __builtin_amdgcn_mfma_f32_16x16x32_bf16(a0, b0, acc[jl], 0, 0, 0);
            acc[jl] = __builtin_amdgcn_mfma_f32_16x16x32_bf16(a1, b1, acc[jl], 0, 0, 0);
        }
    }

    const int px_base = n0 + (w & 3) * 16 + g * 4;
    #pragma unroll
    for (int jl = 0; jl < 5; ++jl) {
        int rbase = rhalf + jl * 16;
        if (rbase == 0) {
            #pragma unroll
            for (int rr = 0; rr < 4; ++rr)
                qb[((size_t)ib * N_PIX + px_base + rr) * 16 + l15] = f2bf(acc[jl][rr]);
        } else if (rbase == 16) {
            #pragma unroll
            for (int rr = 0; rr < 4; ++rr)
                kb[((size_t)ib * N_PIX + px_base + rr) * 16 + l15] = f2bf(acc[jl][rr]);
        } else {
            int c = rbase - 32 + l15;
            short4 s;
            s.x = f2bf(acc[jl][0]); s.y = f2bf(acc[jl][1]);
            s.z = f2bf(acc[jl][2]); s.w = f2bf(acc[jl][3]);
            *(short4*)&vb[((size_t)ib * DV + c) * N_PIX + px_base] = s;
        }
    }
}

// ---------------------------------------------------------------------------
// K2: MFMA flash attention, V-in-registers, 3-way m-split (chunks 22/22/20).
// grid 768: pb = bid&3, mh = (bid>>2)%3, nt = bid/12. 3 blocks/CU.
// Partials: mh=0 -> f32 in out1/out2 c<128 (merged in place);
// mh=1,2 -> bf16 tiled [slot=pb*2+(mh-1)][nt][c][64] in feat region,
// written via LDS repack (full-line int4 stores - r7's 32B-segment lesson).
// ---------------------------------------------------------------------------
__global__ __launch_bounds__(256, 4) void attn_kernel(
    const short* __restrict__ qg, const short* __restrict__ kg,
    const short* __restrict__ vg,
    float* __restrict__ out1, float* __restrict__ out2,
    short* __restrict__ featp, float* __restrict__ lpart)
{
    __shared__ short k_lds[64 * 24];   // [m][d], pitch 24 shorts (48B)
    __shared__ short p_lds[64 * 72];   // [n][m] in loop; [c][66] repack at end

    const int tid = threadIdx.x;
    const int lane = tid & 63;
    const int w = tid >> 6;
    const int gk = lane >> 4;
    const int l15 = lane & 15;

    const int B_ = blockIdx.x;
    const int pb = B_ & 3;
    const int mh = (B_ >> 2) % 3;
    const int nt = B_ / 12;
    const int n0 = nt * 64;
    const int br = pb >> 1, b = pb & 1;
    const int tstart = mh * 22;
    const int tend = (mh == 2) ? 64 : tstart + 22;   // 22/22/20, all even

    const short* qp = qg + (size_t)pb * N_PIX * 16;
    const short* kp = kg + (size_t)((br ^ 1) * 2 + b) * N_PIX * 16;
    const short* vp = vg + (size_t)pb * DV * N_PIX;

    bf16x8 aq = {};
    if (lane < 32)
        aq = *(const bf16x8*)&qp[(size_t)(n0 + w * 16 + l15) * 16 + gk * 8];

    f32x4 acc[2][4];
    #pragma unroll
    for (int cc = 0; cc < 2; ++cc)
        #pragma unroll
        for (int nb = 0; nb < 4; ++nb) acc[cc][nb] = (f32x4){0.f, 0.f, 0.f, 0.f};
    float lsum[4] = {0.f, 0.f, 0.f, 0.f};

    const short* vbase = vp + (size_t)(w * 32 + l15) * N_PIX + gk * 8;
    const int krow = tid - 192;

    int4 vbuf0[4], vbuf1[4];
    int4 kr0 = {}, kr1 = {};

    {   // prologue: chunk tstart -> V regs, K LDS
        #pragma unroll
        for (int cc = 0; cc < 2; ++cc)
            #pragma unroll
            for (int m2 = 0; m2 < 2; ++m2)
                vbuf0[cc * 2 + m2] = *(const int4*)
                    &vbase[(size_t)cc * 16 * N_PIX + tstart * 64 + m2 * 32];
        if (tid >= 192) {
            kr0 = *(const int4*)&kp[(size_t)(tstart * 64 + krow) * 16];
            kr1 = *(const int4*)&kp[(size_t)(tstart * 64 + krow) * 16 + 8];
            *(int4*)&k_lds[krow * 24] = kr0;
            *(int4*)&k_lds[krow * 24 + 8] = kr1;
        }
        __syncthreads();
    }

    for (int t0 = tstart; t0 < tend; t0 += 2) {
        #pragma unroll
        for (int half = 0; half < 2; ++half) {
            const int t = t0 + half;
            int4* vcur = half ? vbuf1 : vbuf0;
            int4* vnxt = half ? vbuf0 : vbuf1;
            if (t + 1 < tend) {
                #pragma unroll
                for (int cc = 0; cc < 2; ++cc)
                    #pragma unroll
                    for (int m2 = 0; m2 < 2; ++m2)
                        vnxt[cc * 2 + m2] = *(const int4*)
                            &vbase[(size_t)cc * 16 * N_PIX + (t + 1) * 64 + m2 * 32];
                if (tid >= 192) {
                    kr0 = *(const int4*)&kp[(size_t)((t + 1) * 64 + krow) * 16];
                    kr1 = *(const int4*)&kp[(size_t)((t + 1) * 64 + krow) * 16 + 8];
                }
            }
            #pragma unroll
            for (int h = 0; h < 4; ++h) {
                bf16x8 bk_ = {};
                if (lane < 32)
                    bk_ = *(const bf16x8*)&k_lds[(h * 16 + l15) * 24 + gk * 8];
                f32x4 s = __builtin_amdgcn_mfma_f32_16x16x32_bf16(
                    aq, bk_, (f32x4){0.f, 0.f, 0.f, 0.f}, 0, 0, 0);
                #pragma unroll
                for (int rr = 0; rr < 4; ++rr) {
                    float e = __expf(s[rr] * 0.25f);
                    lsum[rr] += e;
                    unsigned u = __builtin_bit_cast(unsigned, e);
                    p_lds[(w * 16 + gk * 4 + rr) * 72 + h * 16 + l15] = (short)(u >> 16);
                }
            }
            __syncthreads();
            if (t + 1 < tend && tid >= 192) {
                *(int4*)&k_lds[krow * 24] = kr0;
                *(int4*)&k_lds[krow * 24 + 8] = kr1;
            }
            __builtin_amdgcn_s_setprio(1);
            #pragma unroll
            for (int m2 = 0; m2 < 2; ++m2) {
                #pragma unroll
                for (int nb = 0; nb < 4; ++nb) {
                    bf16x8 bp = *(const bf16x8*)&p_lds[(nb * 16 + l15) * 72 + m2 * 32 + gk * 8];
                    #pragma unroll
                    for (int cc = 0; cc < 2; ++cc) {
                        bf16x8 av = __builtin_bit_cast(bf16x8, vcur[cc * 2 + m2]);
                        acc[cc][nb] = __builtin_amdgcn_mfma_f32_16x16x32_bf16(
                            av, bp, acc[cc][nb], 0, 0, 0);
                    }
                }
            }
            __builtin_amdgcn_s_setprio(0);
            __syncthreads();
        }
    }

    #pragma unroll
    for (int rr = 0; rr < 4; ++rr) {
        float v = lsum[rr];
        v += __shfl_xor(v, 1); v += __shfl_xor(v, 2);
        v += __shfl_xor(v, 4); v += __shfl_xor(v, 8);
        lsum[rr] = v;
    }
    if (l15 == 0) {
        #pragma unroll
        for (int rr = 0; rr < 4; ++rr)
            lpart[(size_t)(pb * 3 + mh) * N_PIX + n0 + w * 16 + gk * 4 + rr] = lsum[rr];
    }

    if (mh == 0) {   // f32 partial at final location (c<128 of out1/out2)
        float* Od = (br ? out2 : out1) + (size_t)b * CCH * N_PIX;
        #pragma unroll
        for (int cc = 0; cc < 2; ++cc)
            #pragma unroll
            for (int nb = 0; nb < 4; ++nb)
                #pragma unroll
                for (int rr = 0; rr < 4; ++rr) {
                    int c = w * 32 + cc * 16 + gk * 4 + rr;
                    Od[(size_t)c * N_PIX + n0 + nb * 16 + l15] = acc[cc][nb][rr];
                }
    } else {
        // bf16 tiled slot, via LDS repack -> full-line int4 stores
        short* Ps = featp + (size_t)(pb * 2 + (mh - 1)) * (64 * 128 * 64)
                          + (size_t)nt * (128 * 64);
        #pragma unroll
        for (int chalf = 0; chalf < 2; ++chalf) {
            if ((w >> 1) == chalf) {   // waves 0,1 -> c 0..63; waves 2,3 -> 64..127
                int crel_base = (w & 1) * 32;
                #pragma unroll
                for (int cc = 0; cc < 2; ++cc)
                    #pragma unroll
                    for (int nb = 0; nb < 4; ++nb)
                        #pragma unroll
                        for (int rr = 0; rr < 4; ++rr) {
                            int crel = crel_base + cc * 16 + gk * 4 + rr;
                            p_lds[crel * 66 + nb * 16 + l15] = f2bf(acc[cc][nb][rr]);
                        }
            }
            __syncthreads();
            for (int idx = tid; idx < 512; idx += 256) {
                int cr = idx >> 3, seg = idx & 7;
                int4 v = *(const int4*)&p_lds[cr * 66 + seg * 8];
                *(int4*)&Ps[(size_t)(chalf * 64 + cr) * 64 + seg * 8] = v;
            }
            __syncthreads();
        }
    }
}

// ---------------------------------------------------------------------------
// K2b: merge 3 partials (1 f32 in-place + 2 bf16 tiles) + epilogue + prep_s.
// grid (128, 2): x = 32-px tile, y = b. block 256.
// ---------------------------------------------------------------------------
__global__ __launch_bounds__(256) void merge_kernel(
    const float* __restrict__ x1, const float* __restrict__ x2,
    const short* __restrict__ featp, const float* __restrict__ lpart,
    const float* __restrict__ gamma_p,
    float* __restrict__ out1, float* __restrict__ out2,
    short* __restrict__ s_t)
{
    __shared__ short st[32 * 264];
    __shared__ float rls[2][32];
    const int tid = threadIdx.x;
    const int px0 = blockIdx.x * 32;
    const int b = blockIdx.y;
    const int nt = blockIdx.x >> 1;
    const int q32 = (blockIdx.x & 1) * 32;
    const float* xa_ = x1 + (size_t)b * CCH * N_PIX;
    const float* xb_ = x2 + (size_t)b * CCH * N_PIX;
    float* o1 = out1 + (size_t)b * CCH * N_PIX;   // holds pb=b   mh=0 f32 partial
    float* o2 = out2 + (size_t)b * CCH * N_PIX;   // holds pb=2+b mh=0 f32 partial
    // bf16 tile slots: slot = pb*2 + (mh-1)
    const short* T10 = featp + (size_t)(b * 2 + 0) * (64 * 128 * 64) + (size_t)nt * (128 * 64);
    const short* T11 = featp + (size_t)(b * 2 + 1) * (64 * 128 * 64) + (size_t)nt * (128 * 64);
    const short* T20 = featp + (size_t)((2 + b) * 2 + 0) * (64 * 128 * 64) + (size_t)nt * (128 * 64);
    const short* T21 = featp + (size_t)((2 + b) * 2 + 1) * (64 * 128 * 64) + (size_t)nt * (128 * 64);

    if (tid < 64) {
        int h = tid >> 5, j = tid & 31;
        int pbh = h ? (2 + b) : b;
        float l = lpart[(size_t)(pbh * 3 + 0) * N_PIX + px0 + j]
                + lpart[(size_t)(pbh * 3 + 1) * N_PIX + px0 + j]
                + lpart[(size_t)(pbh * 3 + 2) * N_PIX + px0 + j];
        rls[h][j] = 1.0f / l;
    }
    __syncthreads();
    const float gmm = gamma_p[0];

    for (int idx = tid; idx < 2048; idx += 256) {
        int c = idx >> 3, p4 = idx & 7;
        size_t off = (size_t)c * N_PIX + px0 + p4 * 4;
        float4 va = *(const float4*)&xa_[off];
        float4 vb2 = *(const float4*)&xb_[off];
        float4 r1, r2;
        if (c < 128) {
            int toff = c * 64 + q32 + p4 * 4;
            float4 pa = *(const float4*)&o1[off];
            float4 pc = *(const float4*)&o2[off];
            float4 a1 = bf4_load(&T10[toff]);
            float4 a2 = bf4_load(&T11[toff]);
            float4 c1 = bf4_load(&T20[toff]);
            float4 c2 = bf4_load(&T21[toff]);
            r1.x = gmm * (pa.x + a1.x + a2.x) * rls[0][p4 * 4 + 0] + va.x;
            r1.y = gmm * (pa.y + a1.y + a2.y) * rls[0][p4 * 4 + 1] + va.y;
            r1.z = gmm * (pa.z + a1.z + a2.z) * rls[0][p4 * 4 + 2] + va.z;
            r1.w = gmm * (pa.w + a1.w + a2.w) * rls[0][p4 * 4 + 3] + va.w;
            r2.x = gmm * (pc.x + c1.x + c2.x) * rls[1][p4 * 4 + 0] + vb2.x;
            r2.y = gmm * (pc.y + c1.y + c2.y) * rls[1][p4 * 4 + 1] + vb2.y;
            r2.z = gmm * (pc.z + c1.z + c2.z) * rls[1][p4 * 4 + 2] + vb2.z;
            r2.w = gmm * (pc.w + c1.w + c2.w) * rls[1][p4 * 4 + 3] + vb2.w;
        } else {
            size_t offl = (size_t)(c - 128) * N_PIX + px0 + p4 * 4;
            float4 val = *(const float4*)&xa_[offl];
            float4 vbl = *(const float4*)&xb_[offl];
            r1.x = gmm * val.x + va.x; r1.y = gmm * val.y + va.y;
            r1.z = gmm * val.z + va.z; r1.w = gmm * val.w + va.w;
            r2.x = gmm * vbl.x + vb2.x; r2.y = gmm * vbl.y + vb2.y;
            r2.z = gmm * vbl.z + vb2.z; r2.w = gmm * vbl.w + vb2.w;
        }
        *(float4*)&o1[off] = r1;
        *(float4*)&o2[off] = r2;
        st[(p4 * 4 + 0) * 264 + c] = f2bf(r1.x + r2.x);
        st[(p4 * 4 + 1) * 264 + c] = f2bf(r1.y + r2.y);
        st[(p4 * 4 + 2) * 264 + c] = f2bf(r1.z + r2.z);
        st[(p4 * 4 + 3) * 264 + c] = f2bf(r1.w + r2.w);
    }
    __syncthreads();
    for (int idx = tid; idx < 1024; idx += 256) {
        int px = idx >> 5, seg = idx & 31;
        int4 v = *(const int4*)&st[px * 264 + seg * 8];
        *(int4*)&s_t[((size_t)b * N_PIX + px0 + px) * CCH + seg * 8] = v;
    }
}

// ---------------------------------------------------------------------------
// K3b: prep_w — blocks <288: Wcat -> bf16 A-fragment order.
//      blocks >=288 (40): pack Wq|Wk|Wv -> wqkv bf16 [160][256].
// ---------------------------------------------------------------------------
__global__ __launch_bounds__(256) void prep_w(
    const float* __restrict__ Wcat,
    const float* __restrict__ Wq, const float* __restrict__ Wk,
    const float* __restrict__ Wv,
    short* __restrict__ wfmt, short* __restrict__ wqkv)
{
    if (blockIdx.x < 288) {
        int idx = blockIdx.x * 256 + threadIdx.x;
        int lane = idx & 63;
        int ocg = (idx >> 6) & 15;
        int chunk = (idx >> 10) & 7;
        int tap = idx >> 13;
        int oc = ocg * 16 + (lane & 15);
        int ic0 = chunk * 32 + (lane >> 4) * 8;
        short8 v;
        #pragma unroll
        for (int j = 0; j < 8; ++j)
            v[j] = f2bf(Wcat[((size_t)oc * CCH + ic0 + j) * 9 + tap]);
        *(short8*)&wfmt[(size_t)idx * 8] = v;
    } else {
        int idx = (blockIdx.x - 288) * 1024 + threadIdx.x * 4;   // 0..40959
        int r = idx >> 8, c = idx & 255;
        const float* src;
        if (r < 16)      src = Wq + (size_t)r * CCH + c;
        else if (r < 32) src = Wk + (size_t)(r - 16) * CCH + c;
        else             src = Wv + (size_t)(r - 32) * CCH + c;
        float4 f = *(const float4*)src;
        short4 s;
        s.x = f2bf(f.x); s.y = f2bf(f.y); s.z = f2bf(f.z); s.w = f2bf(f.w);
        *(short4*)&wqkv[idx] = s;
    }
}

// ---------------------------------------------------------------------------
// K3c: conv as implicit GEMM on MFMA, 1-row strips for 2 blocks/CU.
// grid 512: oc_t = bx&3 (64 oc), pt = bx>>2 (128): b = pt>>6, h0 = pt&63.
// Block: 64 oc x 64 px (1 row); wave wv owns px frag [wv*16, +16), all 4 ocg
// (B-reuse 4 per ds_read). 3-row halo LDS 15.8KB.
// ---------------------------------------------------------------------------
__global__ __launch_bounds__(256, 2) void conv_mfma(
    const short* __restrict__ s_t, const short* __restrict__ wfmt,
    const float* __restrict__ bn_gamma, const float* __restrict__ bn_beta,
    float* __restrict__ feat)
{
    __shared__ short s_lds[198 * 40];   // 3 rows x 66 wi, pitch 40
    const int tid = threadIdx.x;
    const int lane = tid & 63;
    const int wv = tid >> 6;
    const int g = lane >> 4, l15 = lane & 15;

    const int bx = blockIdx.x;
    const int oc_t = bx & 3;
    const int pt = bx >> 2;
    const int b = pt >> 6;
    const int h0 = pt & 63;

    f32x4 acc[4] = {};   // [ocg]

    const short* sbase = s_t + (size_t)b * N_PIX * CCH;
    const short* wf = wfmt + ((size_t)(oc_t * 4) * 64 + lane) * 8;

    for (int ci = 0; ci < 8; ++ci) {
        const int ic0 = ci * 32;
        __syncthreads();
        for (int idx = tid; idx < 792; idx += 256) {
            int seg = idx & 3, pos = idx >> 2;      // pos = row*66 + wi
            int row = pos / 66, wi = pos - row * 66;
            int hr = h0 - 1 + row, w = wi - 1;
            int4 val = {0, 0, 0, 0};
            if (hr >= 0 && hr < 64 && (unsigned)w < 64u)
                val = *(const int4*)&sbase[((size_t)(hr * 64 + w)) * CCH + ic0 + seg * 8];
            *(int4*)&s_lds[pos * 40 + seg * 8] = val;
        }
        __syncthreads();

        const short* wfc = wf + (size_t)ci * 8192;
        bf16x8 a0[4], a1[4];
        #pragma unroll
        for (int j = 0; j < 4; ++j) a0[j] = *(const bf16x8*)&wfc[j * 512];

        for (int tap = 0; tap < 9; ++tap) {
            bf16x8* ac = (tap & 1) ? a1 : a0;
            bf16x8* an = (tap & 1) ? a0 : a1;
            if (tap < 8) {
                const short* wfn = wfc + (size_t)(tap + 1) * 65536;
                #pragma unroll
                for (int j = 0; j < 4; ++j) an[j] = *(const bf16x8*)&wfn[j * 512];
            }
            int ky = (tap >= 6) ? 2 : (tap >= 3 ? 1 : 0);
            int kx = tap - ky * 3;
            bf16x8 bb = *(const bf16x8*)
                &s_lds[(ky * 66 + wv * 16 + l15 + kx) * 40 + g * 8];
            #pragma unroll
            for (int j = 0; j < 4; ++j)
                acc[j] = __builtin_amdgcn_mfma_f32_16x16x32_bf16(
                    ac[j], bb, acc[j], 0, 0, 0);
        }
    }

    const float inv = rsqrtf(1.0f + 1e-5f);
    const int wcol = wv * 16 + l15;
    #pragma unroll
    for (int j = 0; j < 4; ++j) {
        #pragma unroll
        for (int r = 0; r < 4; ++r) {
            int oc = oc_t * 64 + j * 16 + g * 4 + r;
            float y = acc[j][r] * (bn_gamma[oc] * inv) + bn_beta[oc];
            feat[((size_t)b * CCH + oc) * N_PIX + h0 * 64 + wcol] = fmaxf(y, 0.f);
        }
    }
}

// ---------------------------------------------------------------------------
extern "C" void kernel_launch(void* const* d_in, const int* in_sizes, int n_in,
                              void* d_out, int out_size, void* d_ws, size_t ws_size,
                              hipStream_t stream) {
    const float* x1    = (const float*)d_in[0];
    const float* x2    = (const float*)d_in[1];
    const float* Wq    = (const float*)d_in[2];
    const float* bq    = (const float*)d_in[3];
    const float* Wk    = (const float*)d_in[4];
    const float* bk    = (const float*)d_in[5];
    const float* Wv    = (const float*)d_in[6];
    const float* bv    = (const float*)d_in[7];
    const float* gamma = (const float*)d_in[8];
    const float* Wcat  = (const float*)d_in[9];
    const float* bng   = (const float*)d_in[10];
    const float* bnb   = (const float*)d_in[11];

    float* out  = (float*)d_out;
    float* feat = out;                    // hosts 8 bf16 tiled partial slots pre-conv
    float* out1 = out + 2097152;
    float* out2 = out + 4194304;

    short* ws   = (short*)d_ws;
    short* qb   = ws;                     // 262144 shorts
    short* kb   = ws + 262144;            // 262144
    short* vb   = ws + 524288;            // 2097152
    short* s_t  = ws + 2621440;           // 2097152
    short* wfmt = ws + 4718592;           // 589824
    float* lp   = (float*)(ws + 5308416); // 12*4096 f32 l-partials
    short* wqkv = s_t;                    // aliases s_t (dead until merge writes it)

    prep_w<<<328, 256, 0, stream>>>(Wcat, Wq, Wk, Wv, wfmt, wqkv);
    qkv_kernel<<<dim3(64, 4), 512, 0, stream>>>(x1, x2, wqkv, bq, bk, bv, qb, kb, vb);
    attn_kernel<<<768, 256, 0, stream>>>(qb, kb, vb, out1, out2, (short*)feat, lp);
    merge_kernel<<<dim3(128, 2), 256, 0, stream>>>(x1, x2, (const short*)feat, lp, gamma, out1, out2, s_t);
    conv_mfma<<<512, 256, 0, stream>>>(s_t, wfmt, bng, bnb, feat);
}